// Round 3
// baseline (1660.818 us; speedup 1.0000x reference)
//
#include <hip/hip_runtime.h>

#define N_TOK 16384
#define DMODEL 1024
#define NEXP 8
#define CAP 4096
#define HDIM 4096

typedef unsigned short ushort_t;
typedef unsigned int u32;
typedef __attribute__((ext_vector_type(8))) _Float16 half8;
typedef __attribute__((ext_vector_type(8))) ushort_t ushort8;
typedef __attribute__((ext_vector_type(4))) float f32x4;

__device__ inline ushort_t f2h_bits(float f) {
  _Float16 h = (_Float16)f;
  union { _Float16 h; ushort_t u; } cv;
  cv.h = h;
  return cv.u;
}

__device__ inline void gll16(void* lds, const void* g) {
  __builtin_amdgcn_global_load_lds((const __attribute__((address_space(1))) u32*)g,
                                   (__attribute__((address_space(3))) u32*)lds,
                                   16, 0, 0);
}

// ---------------- router: 4 tokens/wave, float4 LDS reads ----------------
__global__ __launch_bounds__(256) void router_kernel(
    const float* __restrict__ x, const float* __restrict__ noise,
    const float* __restrict__ Wr, const float* __restrict__ br,
    const float* __restrict__ Wn, const float* __restrict__ bn,
    int* __restrict__ topi, float* __restrict__ tgate) {
  __shared__ float wrT[NEXP][DMODEL];
  __shared__ float wnT[NEXP][DMODEL];
  int tid = threadIdx.x;
  for (int i = tid; i < NEXP * DMODEL; i += 256) {
    int d = i >> 3, e = i & 7;
    wrT[e][d] = Wr[i];
    wnT[e][d] = Wn[i];
  }
  __syncthreads();
  int wave = tid >> 6, lane = tid & 63;
  int base = (blockIdx.x * 4 + wave) * 4;
  for (int t0 = base; t0 < N_TOK; t0 += 256 * 4 * 4) {
    float aR[4][NEXP], aN[4][NEXP];
#pragma unroll
    for (int tt = 0; tt < 4; ++tt)
#pragma unroll
      for (int e = 0; e < NEXP; ++e) { aR[tt][e] = 0.f; aN[tt][e] = 0.f; }
    for (int c = 0; c < 4; ++c) {
      int d = c * 256 + lane * 4;
      float4 xv[4];
#pragma unroll
      for (int tt = 0; tt < 4; ++tt)
        xv[tt] = *(const float4*)&x[(size_t)(t0 + tt) * DMODEL + d];
#pragma unroll
      for (int e = 0; e < NEXP; ++e) {
        float4 wr4 = *(const float4*)&wrT[e][d];
        float4 wn4 = *(const float4*)&wnT[e][d];
#pragma unroll
        for (int tt = 0; tt < 4; ++tt) {
          aR[tt][e] = fmaf(xv[tt].x, wr4.x, aR[tt][e]);
          aR[tt][e] = fmaf(xv[tt].y, wr4.y, aR[tt][e]);
          aR[tt][e] = fmaf(xv[tt].z, wr4.z, aR[tt][e]);
          aR[tt][e] = fmaf(xv[tt].w, wr4.w, aR[tt][e]);
          aN[tt][e] = fmaf(xv[tt].x, wn4.x, aN[tt][e]);
          aN[tt][e] = fmaf(xv[tt].y, wn4.y, aN[tt][e]);
          aN[tt][e] = fmaf(xv[tt].z, wn4.z, aN[tt][e]);
          aN[tt][e] = fmaf(xv[tt].w, wn4.w, aN[tt][e]);
        }
      }
    }
#pragma unroll
    for (int tt = 0; tt < 4; ++tt)
#pragma unroll
      for (int e = 0; e < NEXP; ++e)
#pragma unroll
        for (int off = 32; off > 0; off >>= 1) {
          aR[tt][e] += __shfl_xor(aR[tt][e], off);
          aN[tt][e] += __shfl_xor(aN[tt][e], off);
        }
#pragma unroll
    for (int tt = 0; tt < 4; ++tt) {
      if (lane == tt) {
        int t = t0 + tt;
        float v0 = -1e30f, v1 = -1e30f;
        int i0 = 0, i1 = 0;
#pragma unroll
        for (int e = 0; e < NEXP; ++e) {
          float lg = aR[tt][e] + br[e];
          float nl = aN[tt][e] + bn[e];
          float sp = fmaxf(nl, 0.f) + log1pf(expf(-fabsf(nl)));
          float nz = fmaf(noise[(size_t)t * NEXP + e], sp, lg);
          if (nz > v0) { v1 = v0; i1 = i0; v0 = nz; i0 = e; }
          else if (nz > v1) { v1 = nz; i1 = e; }
        }
        float e1 = expf(v1 - v0);
        float s = 1.f + e1;
        topi[t * 2] = i0;
        topi[t * 2 + 1] = i1;
        tgate[t * 2] = 1.f / s;
        tgate[t * 2 + 1] = e1 / s;
      }
    }
  }
}

// ------------- scan: arrival-order slots, capacity clamp, inverse map -------------
__global__ __launch_bounds__(1024) void scan_kernel(
    const int* __restrict__ topi, const float* __restrict__ tgate,
    int* __restrict__ tokL, float* __restrict__ gateL, int* __restrict__ counts,
    int* __restrict__ slotOf) {
  __shared__ int s[NEXP][1024];
  __shared__ int run[NEXP][1024];
  int t = threadIdx.x;
#pragma unroll
  for (int e = 0; e < NEXP; ++e) s[e][t] = 0;
#pragma unroll
  for (int i = 0; i < 16; ++i) {
    int n = t * 16 + i;
    s[topi[n * 2]][t]++;
    s[topi[n * 2 + 1]][t]++;
  }
  int myc[NEXP];
#pragma unroll
  for (int e = 0; e < NEXP; ++e) myc[e] = s[e][t];
  __syncthreads();
  for (int off = 1; off < 1024; off <<= 1) {
    int v[NEXP];
#pragma unroll
    for (int e = 0; e < NEXP; ++e) v[e] = (t >= off) ? s[e][t - off] : 0;
    __syncthreads();
#pragma unroll
    for (int e = 0; e < NEXP; ++e) s[e][t] += v[e];
    __syncthreads();
  }
#pragma unroll
  for (int e = 0; e < NEXP; ++e) run[e][t] = s[e][t] - myc[e];
  if (t == 1023) {
#pragma unroll
    for (int e = 0; e < NEXP; ++e) counts[e] = (s[e][1023] < CAP) ? s[e][1023] : CAP;
  }
#pragma unroll
  for (int i = 0; i < 16; ++i) {
    int n = t * 16 + i;
#pragma unroll
    for (int k = 0; k < 2; ++k) {
      int e = topi[n * 2 + k];
      int slot = run[e][t]++;
      if (slot < CAP) {
        tokL[e * CAP + slot] = n;
        gateL[e * CAP + slot] = tgate[n * 2 + k];
        slotOf[n * 2 + k] = e * CAP + slot;
      } else {
        slotOf[n * 2 + k] = -1;
      }
    }
  }
}

// ------------- gather (z = expert) -------------
__global__ __launch_bounds__(256) void gather_kernel(
    const float* __restrict__ x, const int* __restrict__ tokL,
    const int* __restrict__ counts, int e0, ushort_t* __restrict__ Xg_base,
    size_t xg_es) {
  int e = e0 + blockIdx.z;
  const int* etok = tokL + e * CAP;
  ushort_t* Xg = Xg_base + (size_t)blockIdx.z * xg_es;
  int ne = counts[e];
  int slot = blockIdx.x * 2 + (threadIdx.x >> 7);
  if (slot >= ne) return;
  int tok = etok[slot];
  int c = (threadIdx.x & 127) * 8;
  const float4* src = (const float4*)(x + (size_t)tok * DMODEL + c);
  float4 v0 = src[0], v1 = src[1];
  ushort8 o;
  o[0] = f2h_bits(v0.x); o[1] = f2h_bits(v0.y); o[2] = f2h_bits(v0.z); o[3] = f2h_bits(v0.w);
  o[4] = f2h_bits(v1.x); o[5] = f2h_bits(v1.y); o[6] = f2h_bits(v1.z); o[7] = f2h_bits(v1.w);
  *(ushort8*)(Xg + (size_t)slot * DMODEL + c) = o;
}

// ------------- transpose fp32 [R][C] -> f16 [C][R], 64x64 tiles, z = expert -------------
__global__ __launch_bounds__(256) void transpose_cvt_kernel(
    const float* __restrict__ in_base, ushort_t* __restrict__ out_base,
    int R, int C) {
  __shared__ ushort_t ldsT[64 * 66];
  const float* in = in_base + (size_t)blockIdx.z * R * C;
  ushort_t* out = out_base + (size_t)blockIdx.z * R * C;
  int t = threadIdx.x;
  int c0 = blockIdx.x * 64, r0 = blockIdx.y * 64;
  int rr = t >> 4, cc = (t & 15) * 4;
#pragma unroll
  for (int p = 0; p < 4; ++p) {
    int row = r0 + p * 16 + rr;
    float4 v = *(const float4*)&in[(size_t)row * C + c0 + cc];
    ldsT[(cc + 0) * 66 + p * 16 + rr] = f2h_bits(v.x);
    ldsT[(cc + 1) * 66 + p * 16 + rr] = f2h_bits(v.y);
    ldsT[(cc + 2) * 66 + p * 16 + rr] = f2h_bits(v.z);
    ldsT[(cc + 3) * 66 + p * 16 + rr] = f2h_bits(v.w);
  }
  __syncthreads();
  int c_o = t >> 2, r_ch = (t & 3) * 16;
  ushort8 o0, o1;
#pragma unroll
  for (int m = 0; m < 8; ++m) {
    o0[m] = ldsT[c_o * 66 + r_ch + m];
    o1[m] = ldsT[c_o * 66 + r_ch + 8 + m];
  }
  ushort_t* dst = out + (size_t)(c0 + c_o) * R + r0 + r_ch;
  *(ushort8*)dst = o0;
  *(ushort8*)(dst + 8) = o1;
}

// ------------- 128x128 f16 MFMA GEMM, 1D grid, XCD-chunked + col-grouped -------------
// EPI 0: H = f16(relu(acc+bias));  EPI 1: Y[e*CAP+row][col] = acc+bias (f32 store)
// EPI 2: atomicAdd(out[tok][col], (acc+bias)*gate)   [fallback path]
template <int EPI>
__global__ __launch_bounds__(256) void moe_gemm(
    const ushort_t* __restrict__ A_base, size_t a_es,
    const ushort_t* __restrict__ B_base, size_t b_es, int Kdim,
    int nx, int ny, int nxg, int multi,
    const int* __restrict__ counts, int e0,
    const float* __restrict__ bias_base, int bias_stride,
    ushort_t* __restrict__ H_base, size_t h_es,
    float* __restrict__ Y,
    const int* __restrict__ tokL, const float* __restrict__ gateL,
    float* __restrict__ out) {
  int flat = blockIdx.x;
  int ez, local;
  if (multi) { ez = flat & 7; local = flat >> 3; }   // expert == XCD (round-robin i%8)
  else { ez = 0; local = flat; }
  int gsz = ny * nxg;
  int g = local / gsz, rem = local % gsz;
  int row = rem / nxg, xi = rem % nxg;
  int col = g * nxg + xi;
  int e = e0 + ez;
  int ne = counts[e];
  int row0 = row * 128;
  if (row0 >= ne) return;
  int col0 = col * 128;
  const ushort_t* A = A_base + (size_t)ez * a_es;
  const ushort_t* Bt = B_base + (size_t)ez * b_es;
  const float* bias = bias_base + (size_t)e * bias_stride;
  __shared__ __align__(16) ushort_t lds_a[128 * 32];
  __shared__ __align__(16) ushort_t lds_b[128 * 32];
  int tid = threadIdx.x, wave = tid >> 6, lane = tid & 63;
  int wr = wave >> 1, wc = wave & 1;
  f32x4 acc[4][4];
#pragma unroll
  for (int m = 0; m < 4; ++m)
#pragma unroll
    for (int n = 0; n < 4; ++n) acc[m][n] = f32x4{0.f, 0.f, 0.f, 0.f};
  int srow = lane >> 2;
  int soff = (lane & 3) * 16;
  const char* Ab = (const char*)A;
  const char* Bb = (const char*)Bt;
  size_t stride = (size_t)Kdim * 2;
  int lr = lane & 15, lk = (lane >> 4) * 8;
  for (int kt = 0; kt < Kdim; kt += 32) {
#pragma unroll
    for (int i = 0; i < 2; ++i) {
      int c = wave + i * 4;
      gll16((char*)lds_a + c * 1024,
            Ab + (size_t)(row0 + c * 16 + srow) * stride + (size_t)kt * 2 + soff);
      gll16((char*)lds_b + c * 1024,
            Bb + (size_t)(col0 + c * 16 + srow) * stride + (size_t)kt * 2 + soff);
    }
    __syncthreads();
    half8 af[4], bfr[4];
#pragma unroll
    for (int m = 0; m < 4; ++m)
      af[m] = *(const half8*)&lds_a[(wr * 64 + m * 16 + lr) * 32 + lk];
#pragma unroll
    for (int n = 0; n < 4; ++n)
      bfr[n] = *(const half8*)&lds_b[(wc * 64 + n * 16 + lr) * 32 + lk];
#pragma unroll
    for (int m = 0; m < 4; ++m)
#pragma unroll
      for (int n = 0; n < 4; ++n)
        acc[m][n] = __builtin_amdgcn_mfma_f32_16x16x32_f16(af[m], bfr[n], acc[m][n], 0, 0, 0);
    __syncthreads();
  }
  int lq = (lane >> 4) * 4;
  if (EPI == 0) {
    ushort_t* H = H_base + (size_t)ez * h_es;
#pragma unroll
    for (int n = 0; n < 4; ++n) {
      int col_ = col0 + wc * 64 + n * 16 + lr;
      float bv = bias[col_];
#pragma unroll
      for (int m = 0; m < 4; ++m) {
#pragma unroll
        for (int j = 0; j < 4; ++j) {
          int r = row0 + wr * 64 + m * 16 + lq + j;
          float v = acc[m][n][j] + bv;
          H[(size_t)r * HDIM + col_] = f2h_bits(fmaxf(v, 0.f));
        }
      }
    }
  } else if (EPI == 1) {
    float* Yp = Y + (size_t)e * CAP * DMODEL;
    float bv[4];
#pragma unroll
    for (int n = 0; n < 4; ++n) bv[n] = bias[col0 + wc * 64 + n * 16 + lr];
#pragma unroll
    for (int m = 0; m < 4; ++m) {
#pragma unroll
      for (int j = 0; j < 4; ++j) {
        int r = row0 + wr * 64 + m * 16 + lq + j;
        if (r < ne) {
#pragma unroll
          for (int n = 0; n < 4; ++n) {
            int col_ = col0 + wc * 64 + n * 16 + lr;
            Yp[(size_t)r * DMODEL + col_] = acc[m][n][j] + bv[n];
          }
        }
      }
    }
  } else {
    const int* etok = tokL + e * CAP;
    const float* egate = gateL + e * CAP;
    float bv[4];
#pragma unroll
    for (int n = 0; n < 4; ++n) bv[n] = bias[col0 + wc * 64 + n * 16 + lr];
#pragma unroll
    for (int m = 0; m < 4; ++m) {
#pragma unroll
      for (int j = 0; j < 4; ++j) {
        int r = row0 + wr * 64 + m * 16 + lq + j;
        if (r < ne) {
          int tok = etok[r];
          float gt = egate[r];
#pragma unroll
          for (int n = 0; n < 4; ++n) {
            int col_ = col0 + wc * 64 + n * 16 + lr;
            atomicAdd(out + (size_t)tok * DMODEL + col_, (acc[m][n][j] + bv[n]) * gt);
          }
        }
      }
    }
  }
}

// ------------- combine: out[n] = sum_k gate_k * Y[slot_k]  (full overwrite) -------------
__global__ __launch_bounds__(256) void combine_kernel(
    const float* __restrict__ Y, const int* __restrict__ slotOf,
    const float* __restrict__ tgate, float* __restrict__ out) {
  int n = blockIdx.x * 2 + (threadIdx.x >> 7);
  int d = (threadIdx.x & 127) * 8;
  int s0 = slotOf[n * 2], s1 = slotOf[n * 2 + 1];
  float g0 = tgate[n * 2], g1 = tgate[n * 2 + 1];
  float4 a0 = {0.f, 0.f, 0.f, 0.f}, a1 = {0.f, 0.f, 0.f, 0.f};
  if (s0 >= 0) {
    const float4* p = (const float4*)(Y + (size_t)s0 * DMODEL + d);
    float4 v0 = p[0], v1 = p[1];
    a0.x += g0 * v0.x; a0.y += g0 * v0.y; a0.z += g0 * v0.z; a0.w += g0 * v0.w;
    a1.x += g0 * v1.x; a1.y += g0 * v1.y; a1.z += g0 * v1.z; a1.w += g0 * v1.w;
  }
  if (s1 >= 0) {
    const float4* p = (const float4*)(Y + (size_t)s1 * DMODEL + d);
    float4 v0 = p[0], v1 = p[1];
    a0.x += g1 * v0.x; a0.y += g1 * v0.y; a0.z += g1 * v0.z; a0.w += g1 * v0.w;
    a1.x += g1 * v1.x; a1.y += g1 * v1.y; a1.z += g1 * v1.z; a1.w += g1 * v1.w;
  }
  float4* o = (float4*)(out + (size_t)n * DMODEL + d);
  o[0] = a0;
  o[1] = a1;
}

extern "C" void kernel_launch(void* const* d_in, const int* in_sizes, int n_in,
                              void* d_out, int out_size, void* d_ws, size_t ws_size,
                              hipStream_t stream) {
  const float* x = (const float*)d_in[0];
  const float* noise = (const float*)d_in[1];
  const float* Wr = (const float*)d_in[2];
  const float* br = (const float*)d_in[3];
  const float* Wn = (const float*)d_in[4];
  const float* bn = (const float*)d_in[5];
  const float* W1 = (const float*)d_in[6];
  const float* b1 = (const float*)d_in[7];
  const float* W2 = (const float*)d_in[8];
  const float* b2 = (const float*)d_in[9];
  float* out = (float*)d_out;

  char* ws = (char*)d_ws;
  int* topi = (int*)ws;              ws += (size_t)N_TOK * 2 * 4;
  float* tgate = (float*)ws;         ws += (size_t)N_TOK * 2 * 4;
  int* tokL = (int*)ws;              ws += (size_t)NEXP * CAP * 4;
  float* gateL = (float*)ws;         ws += (size_t)NEXP * CAP * 4;
  int* slotOf = (int*)ws;            ws += (size_t)N_TOK * 2 * 4;
  int* counts = (int*)ws;            ws += 256;

  const size_t XG_E = (size_t)CAP * DMODEL;
  const size_t W1_E = (size_t)HDIM * DMODEL;
  const size_t W2_E = (size_t)DMODEL * HDIM;
  const size_t H_E  = (size_t)CAP * HDIM;
  const size_t Y_E  = (size_t)CAP * DMODEL;     // f32 per expert

  router_kernel<<<256, 256, 0, stream>>>(x, noise, Wr, br, Wn, bn, topi, tgate);
  scan_kernel<<<1, 1024, 0, stream>>>(topi, tgate, tokL, gateL, counts, slotOf);

  size_t used = (size_t)(ws - (char*)d_ws);
  size_t need_fast = 2ull * NEXP * (XG_E + W1_E + W2_E + H_E) + 4ull * NEXP * Y_E + 1024;
  bool fast = (ws_size - used) >= need_fast;

  if (fast) {
    ushort_t* Xg_all = (ushort_t*)ws;   ws += 2ull * NEXP * XG_E;
    ushort_t* W1t_all = (ushort_t*)ws;  ws += 2ull * NEXP * W1_E;
    ushort_t* W2t_all = (ushort_t*)ws;  ws += 2ull * NEXP * W2_E;
    ushort_t* H_all = (ushort_t*)ws;    ws += 2ull * NEXP * H_E;
    float* Y = (float*)ws;              ws += 4ull * NEXP * Y_E;

    gather_kernel<<<dim3(CAP / 2, 1, NEXP), 256, 0, stream>>>(
        x, tokL, counts, 0, Xg_all, XG_E);
    transpose_cvt_kernel<<<dim3(HDIM / 64, DMODEL / 64, NEXP), 256, 0, stream>>>(
        W1, W1t_all, DMODEL, HDIM);
    transpose_cvt_kernel<<<dim3(DMODEL / 64, HDIM / 64, NEXP), 256, 0, stream>>>(
        W2, W2t_all, HDIM, DMODEL);
    // GEMM1: per expert 32x32 blocks; nxg=1 -> B-panel reused consecutively, Xg (4MB) L2-resident
    moe_gemm<0><<<dim3(NEXP * 32 * 32), 256, 0, stream>>>(
        Xg_all, XG_E, W1t_all, W1_E, DMODEL, 32, 32, 1, 1, counts, 0, b1, HDIM,
        H_all, H_E, nullptr, nullptr, nullptr, nullptr);
    // GEMM2: per expert 32x8 blocks; nxg=4 -> H-panel fetched ~once, 4MB W2t col-group resident
    moe_gemm<1><<<dim3(NEXP * 32 * 8), 256, 0, stream>>>(
        H_all, H_E, W2t_all, W2_E, HDIM, 8, 32, 4, 1, counts, 0, b2, DMODEL,
        nullptr, 0, Y, nullptr, nullptr, nullptr);
    combine_kernel<<<dim3(N_TOK / 2), 256, 0, stream>>>(Y, slotOf, tgate, out);
  } else {
    hipMemsetAsync(d_out, 0, (size_t)out_size * sizeof(float), stream);
    ushort_t* Xg = (ushort_t*)ws;   ws += 2ull * XG_E;
    ushort_t* W1t = (ushort_t*)ws;  ws += 2ull * W1_E;
    ushort_t* W2t = (ushort_t*)ws;  ws += 2ull * W2_E;
    ushort_t* H = (ushort_t*)ws;    ws += 2ull * H_E;
    for (int e = 0; e < NEXP; ++e) {
      gather_kernel<<<dim3(CAP / 2, 1, 1), 256, 0, stream>>>(
          x, tokL, counts, e, Xg, 0);
      transpose_cvt_kernel<<<dim3(HDIM / 64, DMODEL / 64, 1), 256, 0, stream>>>(
          W1 + (size_t)e * W1_E, W1t, DMODEL, HDIM);
      transpose_cvt_kernel<<<dim3(DMODEL / 64, HDIM / 64, 1), 256, 0, stream>>>(
          W2 + (size_t)e * W2_E, W2t, HDIM, DMODEL);
      moe_gemm<0><<<dim3(32 * 32), 256, 0, stream>>>(
          Xg, 0, W1t, 0, DMODEL, 32, 32, 1, 0, counts, e, b1, HDIM,
          H, 0, nullptr, nullptr, nullptr, nullptr);
      moe_gemm<2><<<dim3(32 * 8), 256, 0, stream>>>(
          H, 0, W2t, 0, HDIM, 8, 32, 4, 0, counts, e, b2, DMODEL,
          nullptr, 0, nullptr, tokL, gateL, out);
    }
  }
}

// Round 4
// 1221.168 us; speedup vs baseline: 1.3600x; 1.3600x over previous
//
#include <hip/hip_runtime.h>

#define N_TOK 16384
#define DMODEL 1024
#define NEXP 8
#define CAP 4096
#define HDIM 4096

typedef unsigned short ushort_t;
typedef unsigned int u32;
typedef __attribute__((ext_vector_type(8))) _Float16 half8;
typedef __attribute__((ext_vector_type(8))) ushort_t ushort8;
typedef __attribute__((ext_vector_type(4))) float f32x4;

__device__ inline ushort_t f2h_bits(float f) {
  _Float16 h = (_Float16)f;
  union { _Float16 h; ushort_t u; } cv;
  cv.h = h;
  return cv.u;
}
__device__ inline float h2f(ushort_t u) {
  union { ushort_t u; _Float16 h; } cv;
  cv.u = u;
  return (float)cv.h;
}

__device__ inline void gll16(void* lds, const void* g) {
  __builtin_amdgcn_global_load_lds((const __attribute__((address_space(1))) u32*)g,
                                   (__attribute__((address_space(3))) u32*)lds,
                                   16, 0, 0);
}

// ---------------- prep: Wr/Wn [D][E] -> [E][D] f32 ----------------
__global__ __launch_bounds__(256) void routerW_prep(
    const float* __restrict__ Wr, const float* __restrict__ Wn,
    float* __restrict__ wrT, float* __restrict__ wnT) {
  int i = blockIdx.x * 256 + threadIdx.x;   // 8192 total
  int d = i >> 3, e = i & 7;
  wrT[e * DMODEL + d] = Wr[i];
  wnT[e * DMODEL + d] = Wn[i];
}

// ---------------- router v3: weights from L2, 4 tokens/wave, no LDS ----------------
__global__ __launch_bounds__(256, 4) void router_kernel(
    const float* __restrict__ x, const float* __restrict__ noise,
    const float* __restrict__ wrT, const float* __restrict__ wnT,
    const float* __restrict__ br, const float* __restrict__ bn,
    int* __restrict__ topi, float* __restrict__ tgate) {
  int tid = threadIdx.x;
  int wave = tid >> 6, lane = tid & 63;
  int grp0 = blockIdx.x * 4 + wave;
  for (int grp = grp0; grp < N_TOK / 4; grp += gridDim.x * 4) {
    int t0 = grp * 4;
    float aR[4][NEXP], aN[4][NEXP];
#pragma unroll
    for (int tt = 0; tt < 4; ++tt)
#pragma unroll
      for (int e = 0; e < NEXP; ++e) { aR[tt][e] = 0.f; aN[tt][e] = 0.f; }
#pragma unroll 2
    for (int it = 0; it < 16; ++it) {
      int d = it * 64 + lane;
      float xv0 = x[(size_t)t0 * DMODEL + d];
      float xv1 = x[(size_t)(t0 + 1) * DMODEL + d];
      float xv2 = x[(size_t)(t0 + 2) * DMODEL + d];
      float xv3 = x[(size_t)(t0 + 3) * DMODEL + d];
#pragma unroll
      for (int e = 0; e < NEXP; ++e) {
        float wr = wrT[e * DMODEL + d];
        float wn = wnT[e * DMODEL + d];
        aR[0][e] = fmaf(xv0, wr, aR[0][e]);
        aR[1][e] = fmaf(xv1, wr, aR[1][e]);
        aR[2][e] = fmaf(xv2, wr, aR[2][e]);
        aR[3][e] = fmaf(xv3, wr, aR[3][e]);
        aN[0][e] = fmaf(xv0, wn, aN[0][e]);
        aN[1][e] = fmaf(xv1, wn, aN[1][e]);
        aN[2][e] = fmaf(xv2, wn, aN[2][e]);
        aN[3][e] = fmaf(xv3, wn, aN[3][e]);
      }
    }
#pragma unroll
    for (int tt = 0; tt < 4; ++tt)
#pragma unroll
      for (int e = 0; e < NEXP; ++e)
#pragma unroll
        for (int off = 32; off > 0; off >>= 1) {
          aR[tt][e] += __shfl_xor(aR[tt][e], off);
          aN[tt][e] += __shfl_xor(aN[tt][e], off);
        }
#pragma unroll
    for (int tt = 0; tt < 4; ++tt) {
      if (lane == tt) {
        int t = t0 + tt;
        float v0 = -1e30f, v1 = -1e30f;
        int i0 = 0, i1 = 0;
#pragma unroll
        for (int e = 0; e < NEXP; ++e) {
          float lg = aR[tt][e] + br[e];
          float nl = aN[tt][e] + bn[e];
          float sp = fmaxf(nl, 0.f) + log1pf(expf(-fabsf(nl)));
          float nz = fmaf(noise[(size_t)t * NEXP + e], sp, lg);
          if (nz > v0) { v1 = v0; i1 = i0; v0 = nz; i0 = e; }
          else if (nz > v1) { v1 = nz; i1 = e; }
        }
        float e1 = expf(v1 - v0);
        float s = 1.f + e1;
        topi[t * 2] = i0;
        topi[t * 2 + 1] = i1;
        tgate[t * 2] = 1.f / s;
        tgate[t * 2 + 1] = e1 / s;
      }
    }
  }
}

// ------------- scan: arrival-order slots, capacity clamp, inverse map -------------
__global__ __launch_bounds__(1024) void scan_kernel(
    const int* __restrict__ topi, const float* __restrict__ tgate,
    int* __restrict__ tokL, float* __restrict__ gateL, int* __restrict__ counts,
    int* __restrict__ slotOf) {
  __shared__ int s[NEXP][1024];
  __shared__ int run[NEXP][1024];
  int t = threadIdx.x;
#pragma unroll
  for (int e = 0; e < NEXP; ++e) s[e][t] = 0;
#pragma unroll
  for (int i = 0; i < 16; ++i) {
    int n = t * 16 + i;
    s[topi[n * 2]][t]++;
    s[topi[n * 2 + 1]][t]++;
  }
  int myc[NEXP];
#pragma unroll
  for (int e = 0; e < NEXP; ++e) myc[e] = s[e][t];
  __syncthreads();
  for (int off = 1; off < 1024; off <<= 1) {
    int v[NEXP];
#pragma unroll
    for (int e = 0; e < NEXP; ++e) v[e] = (t >= off) ? s[e][t - off] : 0;
    __syncthreads();
#pragma unroll
    for (int e = 0; e < NEXP; ++e) s[e][t] += v[e];
    __syncthreads();
  }
#pragma unroll
  for (int e = 0; e < NEXP; ++e) run[e][t] = s[e][t] - myc[e];
  if (t == 1023) {
#pragma unroll
    for (int e = 0; e < NEXP; ++e) counts[e] = (s[e][1023] < CAP) ? s[e][1023] : CAP;
  }
#pragma unroll
  for (int i = 0; i < 16; ++i) {
    int n = t * 16 + i;
#pragma unroll
    for (int k = 0; k < 2; ++k) {
      int e = topi[n * 2 + k];
      int slot = run[e][t]++;
      if (slot < CAP) {
        tokL[e * CAP + slot] = n;
        gateL[e * CAP + slot] = tgate[n * 2 + k];
        slotOf[n * 2 + k] = e * CAP + slot;
      } else {
        slotOf[n * 2 + k] = -1;
      }
    }
  }
}

// ------------- gather (z = expert) -------------
__global__ __launch_bounds__(256) void gather_kernel(
    const float* __restrict__ x, const int* __restrict__ tokL,
    const int* __restrict__ counts, int e0, ushort_t* __restrict__ Xg_base,
    size_t xg_es) {
  int e = e0 + blockIdx.z;
  const int* etok = tokL + e * CAP;
  ushort_t* Xg = Xg_base + (size_t)blockIdx.z * xg_es;
  int ne = counts[e];
  int slot = blockIdx.x * 2 + (threadIdx.x >> 7);
  if (slot >= ne) return;
  int tok = etok[slot];
  int c = (threadIdx.x & 127) * 8;
  const float4* src = (const float4*)(x + (size_t)tok * DMODEL + c);
  float4 v0 = src[0], v1 = src[1];
  ushort8 o;
  o[0] = f2h_bits(v0.x); o[1] = f2h_bits(v0.y); o[2] = f2h_bits(v0.z); o[3] = f2h_bits(v0.w);
  o[4] = f2h_bits(v1.x); o[5] = f2h_bits(v1.y); o[6] = f2h_bits(v1.z); o[7] = f2h_bits(v1.w);
  *(ushort8*)(Xg + (size_t)slot * DMODEL + c) = o;
}

// ------------- transpose fp32 [R][C] -> f16 [C][R], 64x64 tiles, z = expert -------------
__global__ __launch_bounds__(256) void transpose_cvt_kernel(
    const float* __restrict__ in_base, ushort_t* __restrict__ out_base,
    int R, int C) {
  __shared__ ushort_t ldsT[64 * 66];
  const float* in = in_base + (size_t)blockIdx.z * R * C;
  ushort_t* out = out_base + (size_t)blockIdx.z * R * C;
  int t = threadIdx.x;
  int c0 = blockIdx.x * 64, r0 = blockIdx.y * 64;
  int rr = t >> 4, cc = (t & 15) * 4;
#pragma unroll
  for (int p = 0; p < 4; ++p) {
    int row = r0 + p * 16 + rr;
    float4 v = *(const float4*)&in[(size_t)row * C + c0 + cc];
    ldsT[(cc + 0) * 66 + p * 16 + rr] = f2h_bits(v.x);
    ldsT[(cc + 1) * 66 + p * 16 + rr] = f2h_bits(v.y);
    ldsT[(cc + 2) * 66 + p * 16 + rr] = f2h_bits(v.z);
    ldsT[(cc + 3) * 66 + p * 16 + rr] = f2h_bits(v.w);
  }
  __syncthreads();
  int c_o = t >> 2, r_ch = (t & 3) * 16;
  ushort8 o0, o1;
#pragma unroll
  for (int m = 0; m < 8; ++m) {
    o0[m] = ldsT[c_o * 66 + r_ch + m];
    o1[m] = ldsT[c_o * 66 + r_ch + 8 + m];
  }
  ushort_t* dst = out + (size_t)(c0 + c_o) * R + r0 + r_ch;
  *(ushort8*)dst = o0;
  *(ushort8*)(dst + 8) = o1;
}

// ------------- 128x128 f16 MFMA GEMM, 1D grid: ez = flat % nez (expert<->XCD) -------------
// EPI 0: H[ez] = f16(relu(acc+bias))
// EPI 1: Yh[e*CAP+row][col] = f16(acc+bias)
// EPI 2: atomicAdd(out[tok][col], (acc+bias)*gate)   [fallback]
template <int EPI>
__global__ __launch_bounds__(256) void moe_gemm(
    const ushort_t* __restrict__ A_base, size_t a_es,
    const ushort_t* __restrict__ B_base, size_t b_es, int Kdim,
    int nez, int ny, int nxg,
    const int* __restrict__ counts, int e0,
    const float* __restrict__ bias_base, int bias_stride,
    ushort_t* __restrict__ H_base, size_t h_es,
    ushort_t* __restrict__ Yh,
    const int* __restrict__ tokL, const float* __restrict__ gateL,
    float* __restrict__ out) {
  int flat = blockIdx.x;
  int ez = flat % nez;
  int local = flat / nez;
  int gsz = ny * nxg;
  int g = local / gsz, rem = local % gsz;
  int row = rem / nxg, xi = rem % nxg;
  int col = g * nxg + xi;
  int e = e0 + ez;
  int ne = counts[e];
  int row0 = row * 128;
  if (row0 >= ne) return;
  int col0 = col * 128;
  const ushort_t* A = A_base + (size_t)ez * a_es;
  const ushort_t* Bt = B_base + (size_t)ez * b_es;
  const float* bias = bias_base + (size_t)e * bias_stride;
  __shared__ __align__(16) ushort_t lds_a[128 * 32];
  __shared__ __align__(16) ushort_t lds_b[128 * 32];
  int tid = threadIdx.x, wave = tid >> 6, lane = tid & 63;
  int wr = wave >> 1, wc = wave & 1;
  f32x4 acc[4][4];
#pragma unroll
  for (int m = 0; m < 4; ++m)
#pragma unroll
    for (int n = 0; n < 4; ++n) acc[m][n] = f32x4{0.f, 0.f, 0.f, 0.f};
  int srow = lane >> 2;
  int soff = (lane & 3) * 16;
  const char* Ab = (const char*)A;
  const char* Bb = (const char*)Bt;
  size_t stride = (size_t)Kdim * 2;
  int lr = lane & 15, lk = (lane >> 4) * 8;
  for (int kt = 0; kt < Kdim; kt += 32) {
#pragma unroll
    for (int i = 0; i < 2; ++i) {
      int c = wave + i * 4;
      gll16((char*)lds_a + c * 1024,
            Ab + (size_t)(row0 + c * 16 + srow) * stride + (size_t)kt * 2 + soff);
      gll16((char*)lds_b + c * 1024,
            Bb + (size_t)(col0 + c * 16 + srow) * stride + (size_t)kt * 2 + soff);
    }
    __syncthreads();
    half8 af[4], bfr[4];
#pragma unroll
    for (int m = 0; m < 4; ++m)
      af[m] = *(const half8*)&lds_a[(wr * 64 + m * 16 + lr) * 32 + lk];
#pragma unroll
    for (int n = 0; n < 4; ++n)
      bfr[n] = *(const half8*)&lds_b[(wc * 64 + n * 16 + lr) * 32 + lk];
#pragma unroll
    for (int m = 0; m < 4; ++m)
#pragma unroll
      for (int n = 0; n < 4; ++n)
        acc[m][n] = __builtin_amdgcn_mfma_f32_16x16x32_f16(af[m], bfr[n], acc[m][n], 0, 0, 0);
    __syncthreads();
  }
  int lq = (lane >> 4) * 4;
  if (EPI == 0) {
    ushort_t* H = H_base + (size_t)ez * h_es;
#pragma unroll
    for (int n = 0; n < 4; ++n) {
      int col_ = col0 + wc * 64 + n * 16 + lr;
      float bv = bias[col_];
#pragma unroll
      for (int m = 0; m < 4; ++m) {
#pragma unroll
        for (int j = 0; j < 4; ++j) {
          int r = row0 + wr * 64 + m * 16 + lq + j;
          float v = acc[m][n][j] + bv;
          H[(size_t)r * HDIM + col_] = f2h_bits(fmaxf(v, 0.f));
        }
      }
    }
  } else if (EPI == 1) {
    ushort_t* Yp = Yh + (size_t)e * CAP * DMODEL;
    float bv[4];
#pragma unroll
    for (int n = 0; n < 4; ++n) bv[n] = bias[col0 + wc * 64 + n * 16 + lr];
#pragma unroll
    for (int m = 0; m < 4; ++m) {
#pragma unroll
      for (int j = 0; j < 4; ++j) {
        int r = row0 + wr * 64 + m * 16 + lq + j;
        if (r < ne) {
#pragma unroll
          for (int n = 0; n < 4; ++n) {
            int col_ = col0 + wc * 64 + n * 16 + lr;
            Yp[(size_t)r * DMODEL + col_] = f2h_bits(acc[m][n][j] + bv[n]);
          }
        }
      }
    }
  } else {
    const int* etok = tokL + e * CAP;
    const float* egate = gateL + e * CAP;
    float bv[4];
#pragma unroll
    for (int n = 0; n < 4; ++n) bv[n] = bias[col0 + wc * 64 + n * 16 + lr];
#pragma unroll
    for (int m = 0; m < 4; ++m) {
#pragma unroll
      for (int j = 0; j < 4; ++j) {
        int r = row0 + wr * 64 + m * 16 + lq + j;
        if (r < ne) {
          int tok = etok[r];
          float gt = egate[r];
#pragma unroll
          for (int n = 0; n < 4; ++n) {
            int col_ = col0 + wc * 64 + n * 16 + lr;
            atomicAdd(out + (size_t)tok * DMODEL + col_, (acc[m][n][j] + bv[n]) * gt);
          }
        }
      }
    }
  }
}

// ------------- combine: out[n] = sum_k gate_k * Yh[slot_k]  (full overwrite) -------------
__global__ __launch_bounds__(256) void combine_kernel(
    const ushort_t* __restrict__ Yh, const int* __restrict__ slotOf,
    const float* __restrict__ tgate, float* __restrict__ out) {
  int n = blockIdx.x * 2 + (threadIdx.x >> 7);
  int d = (threadIdx.x & 127) * 8;
  int s0 = slotOf[n * 2], s1 = slotOf[n * 2 + 1];
  float g0 = tgate[n * 2], g1 = tgate[n * 2 + 1];
  float acc[8];
#pragma unroll
  for (int j = 0; j < 8; ++j) acc[j] = 0.f;
  if (s0 >= 0) {
    ushort8 v = *(const ushort8*)(Yh + (size_t)s0 * DMODEL + d);
#pragma unroll
    for (int j = 0; j < 8; ++j) acc[j] = fmaf(g0, h2f(v[j]), acc[j]);
  }
  if (s1 >= 0) {
    ushort8 v = *(const ushort8*)(Yh + (size_t)s1 * DMODEL + d);
#pragma unroll
    for (int j = 0; j < 8; ++j) acc[j] = fmaf(g1, h2f(v[j]), acc[j]);
  }
  float4* o = (float4*)(out + (size_t)n * DMODEL + d);
  o[0] = float4{acc[0], acc[1], acc[2], acc[3]};
  o[1] = float4{acc[4], acc[5], acc[6], acc[7]};
}

extern "C" void kernel_launch(void* const* d_in, const int* in_sizes, int n_in,
                              void* d_out, int out_size, void* d_ws, size_t ws_size,
                              hipStream_t stream) {
  const float* x = (const float*)d_in[0];
  const float* noise = (const float*)d_in[1];
  const float* Wr = (const float*)d_in[2];
  const float* br = (const float*)d_in[3];
  const float* Wn = (const float*)d_in[4];
  const float* bn = (const float*)d_in[5];
  const float* W1 = (const float*)d_in[6];
  const float* b1 = (const float*)d_in[7];
  const float* W2 = (const float*)d_in[8];
  const float* b2 = (const float*)d_in[9];
  float* out = (float*)d_out;

  char* ws = (char*)d_ws;
  int* topi = (int*)ws;              ws += (size_t)N_TOK * 2 * 4;
  float* tgate = (float*)ws;         ws += (size_t)N_TOK * 2 * 4;
  int* tokL = (int*)ws;              ws += (size_t)NEXP * CAP * 4;
  float* gateL = (float*)ws;         ws += (size_t)NEXP * CAP * 4;
  int* slotOf = (int*)ws;            ws += (size_t)N_TOK * 2 * 4;
  int* counts = (int*)ws;            ws += 256;
  float* wrT_g = (float*)ws;         ws += (size_t)NEXP * DMODEL * 4;
  float* wnT_g = (float*)ws;         ws += (size_t)NEXP * DMODEL * 4;

  const size_t XG_E = (size_t)CAP * DMODEL;      // f16 elems
  const size_t W1_E = (size_t)HDIM * DMODEL;
  const size_t W2_E = (size_t)DMODEL * HDIM;
  const size_t H_E  = (size_t)CAP * HDIM;
  const size_t Y_E  = (size_t)CAP * DMODEL;

  routerW_prep<<<32, 256, 0, stream>>>(Wr, Wn, wrT_g, wnT_g);
  router_kernel<<<1024, 256, 0, stream>>>(x, noise, wrT_g, wnT_g, br, bn, topi, tgate);
  scan_kernel<<<1, 1024, 0, stream>>>(topi, tgate, tokL, gateL, counts, slotOf);

  size_t used = (size_t)(ws - (char*)d_ws);
  // fast path: Xg_all 64MB + W1t 64MB + W2t 64MB + H4 128MB + Yh 64MB = 384MB
  size_t need_fast = 2ull * NEXP * (XG_E + W1_E + W2_E + Y_E) + 2ull * 4 * H_E + 1024;
  bool fast = (ws_size - used) >= need_fast;

  if (fast) {
    ushort_t* Xg_all = (ushort_t*)ws;   ws += 2ull * NEXP * XG_E;
    ushort_t* W1t_all = (ushort_t*)ws;  ws += 2ull * NEXP * W1_E;
    ushort_t* W2t_all = (ushort_t*)ws;  ws += 2ull * NEXP * W2_E;
    ushort_t* H4 = (ushort_t*)ws;       ws += 2ull * 4 * H_E;
    ushort_t* Yh = (ushort_t*)ws;       ws += 2ull * NEXP * Y_E;

    gather_kernel<<<dim3(CAP / 2, 1, NEXP), 256, 0, stream>>>(
        x, tokL, counts, 0, Xg_all, XG_E);
    transpose_cvt_kernel<<<dim3(HDIM / 64, DMODEL / 64, NEXP), 256, 0, stream>>>(
        W1, W1t_all, DMODEL, HDIM);
    transpose_cvt_kernel<<<dim3(DMODEL / 64, HDIM / 64, NEXP), 256, 0, stream>>>(
        W2, W2t_all, HDIM, DMODEL);
    for (int g = 0; g < 2; ++g) {
      int e0 = g * 4;
      // GEMM1: 4 experts x 32 rows x 32 cols; nxg=1 -> row-walk within col panel
      moe_gemm<0><<<dim3(4 * 32 * 32), 256, 0, stream>>>(
          Xg_all + (size_t)e0 * XG_E, XG_E, W1t_all + (size_t)e0 * W1_E, W1_E, DMODEL,
          4, 32, 1, counts, e0, b1, HDIM, H4, H_E, nullptr, nullptr, nullptr, nullptr);
      // GEMM2: 4 experts x 32 rows x 8 cols; nxg=4 -> A-panel reuse, B col-groups
      moe_gemm<1><<<dim3(4 * 32 * 8), 256, 0, stream>>>(
          H4, H_E, W2t_all + (size_t)e0 * W2_E, W2_E, HDIM,
          4, 32, 4, counts, e0, b2, DMODEL, nullptr, 0, Yh, nullptr, nullptr, nullptr);
    }
    combine_kernel<<<dim3(N_TOK / 2), 256, 0, stream>>>(Yh, slotOf, tgate, out);
  } else {
    hipMemsetAsync(d_out, 0, (size_t)out_size * sizeof(float), stream);
    ushort_t* Xg = (ushort_t*)ws;   ws += 2ull * XG_E;
    ushort_t* W1t = (ushort_t*)ws;  ws += 2ull * W1_E;
    ushort_t* W2t = (ushort_t*)ws;  ws += 2ull * W2_E;
    ushort_t* H = (ushort_t*)ws;    ws += 2ull * H_E;
    for (int e = 0; e < NEXP; ++e) {
      gather_kernel<<<dim3(CAP / 2, 1, 1), 256, 0, stream>>>(
          x, tokL, counts, e, Xg, 0);
      transpose_cvt_kernel<<<dim3(HDIM / 64, DMODEL / 64, 1), 256, 0, stream>>>(
          W1 + (size_t)e * W1_E, W1t, DMODEL, HDIM);
      transpose_cvt_kernel<<<dim3(DMODEL / 64, HDIM / 64, 1), 256, 0, stream>>>(
          W2 + (size_t)e * W2_E, W2t, HDIM, DMODEL);
      moe_gemm<0><<<dim3(32 * 32), 256, 0, stream>>>(
          Xg, 0, W1t, 0, DMODEL, 1, 32, 1, counts, e, b1, HDIM,
          H, 0, nullptr, nullptr, nullptr, nullptr);
      moe_gemm<2><<<dim3(32 * 8), 256, 0, stream>>>(
          H, 0, W2t, 0, HDIM, 1, 32, 4, counts, e, b2, DMODEL,
          nullptr, 0, nullptr, tokL, gateL, out);
    }
  }
}

// Round 5
// 854.931 us; speedup vs baseline: 1.9426x; 1.4284x over previous
//
#include <hip/hip_runtime.h>

#define N_TOK 16384
#define DMODEL 1024
#define NEXP 8
#define CAP 4096
#define HDIM 4096

typedef unsigned short ushort_t;
typedef unsigned int u32;
typedef __attribute__((ext_vector_type(8))) _Float16 half8;
typedef __attribute__((ext_vector_type(8))) ushort_t ushort8;
typedef __attribute__((ext_vector_type(4))) float f32x4;

__device__ inline ushort_t f2h_bits(float f) {
  _Float16 h = (_Float16)f;
  union { _Float16 h; ushort_t u; } cv;
  cv.h = h;
  return cv.u;
}
__device__ inline float h2f(ushort_t u) {
  union { ushort_t u; _Float16 h; } cv;
  cv.u = u;
  return (float)cv.h;
}

__device__ inline void gll16(void* lds, const void* g) {
  __builtin_amdgcn_global_load_lds((const __attribute__((address_space(1))) u32*)g,
                                   (__attribute__((address_space(3))) u32*)lds,
                                   16, 0, 0);
}

// ---------------- prep: Wr/Wn [D][E] -> [E][D] f32 ----------------
__global__ __launch_bounds__(256) void routerW_prep(
    const float* __restrict__ Wr, const float* __restrict__ Wn,
    float* __restrict__ wrT, float* __restrict__ wnT) {
  int i = blockIdx.x * 256 + threadIdx.x;
  int d = i >> 3, e = i & 7;
  wrT[e * DMODEL + d] = Wr[i];
  wnT[e * DMODEL + d] = Wn[i];
}

// ---------------- router: weights from L2, 4 tokens/wave ----------------
__global__ __launch_bounds__(256, 4) void router_kernel(
    const float* __restrict__ x, const float* __restrict__ noise,
    const float* __restrict__ wrT, const float* __restrict__ wnT,
    const float* __restrict__ br, const float* __restrict__ bn,
    int* __restrict__ topi, float* __restrict__ tgate) {
  int tid = threadIdx.x;
  int wave = tid >> 6, lane = tid & 63;
  int grp0 = blockIdx.x * 4 + wave;
  for (int grp = grp0; grp < N_TOK / 4; grp += gridDim.x * 4) {
    int t0 = grp * 4;
    float aR[4][NEXP], aN[4][NEXP];
#pragma unroll
    for (int tt = 0; tt < 4; ++tt)
#pragma unroll
      for (int e = 0; e < NEXP; ++e) { aR[tt][e] = 0.f; aN[tt][e] = 0.f; }
#pragma unroll 2
    for (int it = 0; it < 16; ++it) {
      int d = it * 64 + lane;
      float xv0 = x[(size_t)t0 * DMODEL + d];
      float xv1 = x[(size_t)(t0 + 1) * DMODEL + d];
      float xv2 = x[(size_t)(t0 + 2) * DMODEL + d];
      float xv3 = x[(size_t)(t0 + 3) * DMODEL + d];
#pragma unroll
      for (int e = 0; e < NEXP; ++e) {
        float wr = wrT[e * DMODEL + d];
        float wn = wnT[e * DMODEL + d];
        aR[0][e] = fmaf(xv0, wr, aR[0][e]);
        aR[1][e] = fmaf(xv1, wr, aR[1][e]);
        aR[2][e] = fmaf(xv2, wr, aR[2][e]);
        aR[3][e] = fmaf(xv3, wr, aR[3][e]);
        aN[0][e] = fmaf(xv0, wn, aN[0][e]);
        aN[1][e] = fmaf(xv1, wn, aN[1][e]);
        aN[2][e] = fmaf(xv2, wn, aN[2][e]);
        aN[3][e] = fmaf(xv3, wn, aN[3][e]);
      }
    }
#pragma unroll
    for (int tt = 0; tt < 4; ++tt)
#pragma unroll
      for (int e = 0; e < NEXP; ++e)
#pragma unroll
        for (int off = 32; off > 0; off >>= 1) {
          aR[tt][e] += __shfl_xor(aR[tt][e], off);
          aN[tt][e] += __shfl_xor(aN[tt][e], off);
        }
#pragma unroll
    for (int tt = 0; tt < 4; ++tt) {
      if (lane == tt) {
        int t = t0 + tt;
        float v0 = -1e30f, v1 = -1e30f;
        int i0 = 0, i1 = 0;
#pragma unroll
        for (int e = 0; e < NEXP; ++e) {
          float lg = aR[tt][e] + br[e];
          float nl = aN[tt][e] + bn[e];
          float sp = fmaxf(nl, 0.f) + log1pf(expf(-fabsf(nl)));
          float nz = fmaf(noise[(size_t)t * NEXP + e], sp, lg);
          if (nz > v0) { v1 = v0; i1 = i0; v0 = nz; i0 = e; }
          else if (nz > v1) { v1 = nz; i1 = e; }
        }
        float e1 = expf(v1 - v0);
        float s = 1.f + e1;
        topi[t * 2] = i0;
        topi[t * 2 + 1] = i1;
        tgate[t * 2] = 1.f / s;
        tgate[t * 2 + 1] = e1 / s;
      }
    }
  }
}

// ------------- scan: arrival-order slots, capacity clamp, inverse map -------------
__global__ __launch_bounds__(1024) void scan_kernel(
    const int* __restrict__ topi, const float* __restrict__ tgate,
    int* __restrict__ tokL, float* __restrict__ gateL, int* __restrict__ counts,
    int* __restrict__ slotOf) {
  __shared__ int s[NEXP][1024];
  __shared__ int run[NEXP][1024];
  int t = threadIdx.x;
#pragma unroll
  for (int e = 0; e < NEXP; ++e) s[e][t] = 0;
#pragma unroll
  for (int i = 0; i < 16; ++i) {
    int n = t * 16 + i;
    s[topi[n * 2]][t]++;
    s[topi[n * 2 + 1]][t]++;
  }
  int myc[NEXP];
#pragma unroll
  for (int e = 0; e < NEXP; ++e) myc[e] = s[e][t];
  __syncthreads();
  for (int off = 1; off < 1024; off <<= 1) {
    int v[NEXP];
#pragma unroll
    for (int e = 0; e < NEXP; ++e) v[e] = (t >= off) ? s[e][t - off] : 0;
    __syncthreads();
#pragma unroll
    for (int e = 0; e < NEXP; ++e) s[e][t] += v[e];
    __syncthreads();
  }
#pragma unroll
  for (int e = 0; e < NEXP; ++e) run[e][t] = s[e][t] - myc[e];
  if (t == 1023) {
#pragma unroll
    for (int e = 0; e < NEXP; ++e) counts[e] = (s[e][1023] < CAP) ? s[e][1023] : CAP;
  }
#pragma unroll
  for (int i = 0; i < 16; ++i) {
    int n = t * 16 + i;
#pragma unroll
    for (int k = 0; k < 2; ++k) {
      int e = topi[n * 2 + k];
      int slot = run[e][t]++;
      if (slot < CAP) {
        tokL[e * CAP + slot] = n;
        gateL[e * CAP + slot] = tgate[n * 2 + k];
        slotOf[n * 2 + k] = e * CAP + slot;
      } else {
        slotOf[n * 2 + k] = -1;
      }
    }
  }
}

// ------------- gather (z = expert) -------------
__global__ __launch_bounds__(256) void gather_kernel(
    const float* __restrict__ x, const int* __restrict__ tokL,
    const int* __restrict__ counts, int e0, ushort_t* __restrict__ Xg_base,
    size_t xg_es) {
  int e = e0 + blockIdx.z;
  const int* etok = tokL + e * CAP;
  ushort_t* Xg = Xg_base + (size_t)blockIdx.z * xg_es;
  int ne = counts[e];
  int slot = blockIdx.x * 2 + (threadIdx.x >> 7);
  if (slot >= ne) return;
  int tok = etok[slot];
  int c = (threadIdx.x & 127) * 8;
  const float4* src = (const float4*)(x + (size_t)tok * DMODEL + c);
  float4 v0 = src[0], v1 = src[1];
  ushort8 o;
  o[0] = f2h_bits(v0.x); o[1] = f2h_bits(v0.y); o[2] = f2h_bits(v0.z); o[3] = f2h_bits(v0.w);
  o[4] = f2h_bits(v1.x); o[5] = f2h_bits(v1.y); o[6] = f2h_bits(v1.z); o[7] = f2h_bits(v1.w);
  *(ushort8*)(Xg + (size_t)slot * DMODEL + c) = o;
}

// ------------- transpose fp32 [R][C] -> f16 [C][R], 64x64 tiles, z = expert -------------
__global__ __launch_bounds__(256) void transpose_cvt_kernel(
    const float* __restrict__ in_base, ushort_t* __restrict__ out_base,
    int R, int C) {
  __shared__ ushort_t ldsT[64 * 66];
  const float* in = in_base + (size_t)blockIdx.z * R * C;
  ushort_t* out = out_base + (size_t)blockIdx.z * R * C;
  int t = threadIdx.x;
  int c0 = blockIdx.x * 64, r0 = blockIdx.y * 64;
  int rr = t >> 4, cc = (t & 15) * 4;
#pragma unroll
  for (int p = 0; p < 4; ++p) {
    int row = r0 + p * 16 + rr;
    float4 v = *(const float4*)&in[(size_t)row * C + c0 + cc];
    ldsT[(cc + 0) * 66 + p * 16 + rr] = f2h_bits(v.x);
    ldsT[(cc + 1) * 66 + p * 16 + rr] = f2h_bits(v.y);
    ldsT[(cc + 2) * 66 + p * 16 + rr] = f2h_bits(v.z);
    ldsT[(cc + 3) * 66 + p * 16 + rr] = f2h_bits(v.w);
  }
  __syncthreads();
  int c_o = t >> 2, r_ch = (t & 3) * 16;
  ushort8 o0, o1;
#pragma unroll
  for (int m = 0; m < 8; ++m) {
    o0[m] = ldsT[c_o * 66 + r_ch + m];
    o1[m] = ldsT[c_o * 66 + r_ch + 8 + m];
  }
  ushort_t* dst = out + (size_t)(c0 + c_o) * R + r0 + r_ch;
  *(ushort8*)dst = o0;
  *(ushort8*)(dst + 8) = o1;
}

// ===================== 256x256 x BK=64, 8-wave, double-buffered, swizzled =====================
// A: [M][K] f16, B^T: [N][K] f16. EPI 0: H=f16(relu(acc+bias)); EPI 1: Yh=f16(acc+bias)
// LDS 128 KiB: buf b at b*65536 bytes; A tile [256][64] at +0, B tile [256][64] at +32768.
// XOR swizzle: 16B-block column c16 stored at physical c16 ^ (row&7); staged via
// inverse-swizzled global source + linear global_load_lds dest (both-sides rule).
#define MFMA_Q(QM, QN, FA, FB)                                                      \
  _Pragma("unroll") for (int mp = 0; mp < 4; ++mp)                                  \
  _Pragma("unroll") for (int np = 0; np < 2; ++np)                                  \
  _Pragma("unroll") for (int ks = 0; ks < 2; ++ks)                                  \
    acc[QM][QN][mp][np] = __builtin_amdgcn_mfma_f32_16x16x32_f16(                   \
        FA[mp][ks], FB[np][ks], acc[QM][QN][mp][np], 0, 0, 0);

template <int EPI>
__global__ __launch_bounds__(512, 2) void moe_gemm256(
    const ushort_t* __restrict__ A_all, size_t a_es,
    const ushort_t* __restrict__ B_all, size_t b_es, int Kdim,
    const int* __restrict__ counts, int e0,
    const float* __restrict__ bias_base, int bias_stride,
    ushort_t* __restrict__ HY_base, size_t hy_es) {
  extern __shared__ char ldsc[];
  int flat = blockIdx.x;
  int ez = flat & 3;
  int local = flat >> 2;
  int row, col;
  if (EPI == 0) { col = local >> 4; row = local & 15; }   // 16x16, col-major walk
  else          { row = local >> 2; col = local & 3; }    // 16x4, row-major walk
  int e = e0 + ez;
  int ne = counts[e];
  int row0 = row * 256;
  if (row0 >= ne) return;
  int col0 = col * 256;

  const char* Ab = (const char*)(A_all + (size_t)ez * a_es) + (size_t)row0 * Kdim * 2;
  const char* Bb = (const char*)(B_all + (size_t)ez * b_es) + (size_t)col0 * Kdim * 2;
  const size_t gstrA = (size_t)Kdim * 2;

  int tid = threadIdx.x;
  int wave = tid >> 6, lane = tid & 63;
  int wm = wave >> 2, wn = wave & 3;       // 2 x 4 waves over each 128x128 quadrant
  int lr = lane & 15, lg = lane >> 4;

  f32x4 acc[2][2][4][2];
#pragma unroll
  for (int qm = 0; qm < 2; ++qm)
#pragma unroll
    for (int qn = 0; qn < 2; ++qn)
#pragma unroll
      for (int mp = 0; mp < 4; ++mp)
#pragma unroll
        for (int np = 0; np < 2; ++np) acc[qm][qn][mp][np] = f32x4{0.f, 0.f, 0.f, 0.f};

  // stage one 16KB half-tile: half 0/1 = A rows 0-127/128-255; 2/3 = B rows.
  auto STAGE = [&](char* obuf, int half, int tt) {
    const char* gb = (half < 2) ? (Ab + (size_t)(half * 128) * gstrA)
                                : (Bb + (size_t)((half - 2) * 128) * gstrA);
    gb += (size_t)tt * 128;                 // K offset in bytes (64 elems)
    char* lb = obuf + half * 16384 + wave * 1024;
#pragma unroll
    for (int i = 0; i < 2; ++i) {
      int o = (i * 512 + tid) * 16;
      int r = o >> 7;
      int lc = ((o >> 4) & 7) ^ (r & 7);    // inverse swizzle on global source
      gll16(lb + i * 8192, gb + (size_t)r * gstrA + lc * 16);
    }
  };
  auto LDA = [&](const char* buf, int qm, int mp, int ks) -> half8 {
    int r = qm * 128 + wm * 64 + mp * 16 + lr;
    int c = ((ks * 4 + lg) ^ (r & 7)) * 16;
    return *(const half8*)(buf + r * 128 + c);
  };
  auto LDB = [&](const char* buf, int qn, int np, int ks) -> half8 {
    int r = qn * 128 + wn * 32 + np * 16 + lr;
    int c = ((ks * 4 + lg) ^ (r & 7)) * 16;
    return *(const half8*)(buf + 32768 + r * 128 + c);
  };

  int NT = Kdim >> 6;
  // prologue: stage tile 0; h0-h2 must land (h3 covered by first mid-tile wait)
  STAGE(ldsc, 0, 0); STAGE(ldsc, 1, 0); STAGE(ldsc, 2, 0); STAGE(ldsc, 3, 0);
  asm volatile("s_waitcnt vmcnt(2)" ::: "memory");
  __builtin_amdgcn_s_barrier();

  half8 fA0[4][2], fA1[4][2], fB0[2][2], fB1[2][2];
  for (int t = 0; t < NT; ++t) {
    char* bufc = ldsc + (t & 1) * 65536;
    char* obufc = ldsc + ((t & 1) ^ 1) * 65536;
    bool pf = (t + 1 < NT);
    // ---- P0: Q(0,0)  reads h0,h2 ----
#pragma unroll
    for (int mp = 0; mp < 4; ++mp)
#pragma unroll
      for (int ks = 0; ks < 2; ++ks) fA0[mp][ks] = LDA(bufc, 0, mp, ks);
#pragma unroll
    for (int np = 0; np < 2; ++np)
#pragma unroll
      for (int ks = 0; ks < 2; ++ks) fB0[np][ks] = LDB(bufc, 0, np, ks);
    if (pf) STAGE(obufc, 0, t + 1);
    __builtin_amdgcn_s_setprio(1);
    MFMA_Q(0, 0, fA0, fB0);
    __builtin_amdgcn_s_setprio(0);
    __builtin_amdgcn_s_barrier();
    // ---- P1: Q(1,0)  reads h1 (B0 reused) ----
#pragma unroll
    for (int mp = 0; mp < 4; ++mp)
#pragma unroll
      for (int ks = 0; ks < 2; ++ks) fA1[mp][ks] = LDA(bufc, 1, mp, ks);
    if (pf) STAGE(obufc, 1, t + 1);
    __builtin_amdgcn_s_setprio(1);
    MFMA_Q(1, 0, fA1, fB0);
    __builtin_amdgcn_s_setprio(0);
    if (pf) { asm volatile("s_waitcnt vmcnt(4)" ::: "memory"); }
    else    { asm volatile("s_waitcnt vmcnt(0)" ::: "memory"); }
    __builtin_amdgcn_s_barrier();
    // ---- P2: Q(0,1)  reads h3 (A0 reused) ----
#pragma unroll
    for (int np = 0; np < 2; ++np)
#pragma unroll
      for (int ks = 0; ks < 2; ++ks) fB1[np][ks] = LDB(bufc, 1, np, ks);
    if (pf) STAGE(obufc, 2, t + 1);
    __builtin_amdgcn_s_setprio(1);
    MFMA_Q(0, 1, fA0, fB1);
    __builtin_amdgcn_s_setprio(0);
    __builtin_amdgcn_s_barrier();
    // ---- P3: Q(1,1)  (A1, B1 reused) ----
    if (pf) STAGE(obufc, 3, t + 1);
    __builtin_amdgcn_s_setprio(1);
    MFMA_Q(1, 1, fA1, fB1);
    __builtin_amdgcn_s_setprio(0);
    asm volatile("s_waitcnt vmcnt(2)" ::: "memory");
    __builtin_amdgcn_s_barrier();
  }

  const float* bias = bias_base + (size_t)e * bias_stride;
  int lq = lg * 4;
  if (EPI == 0) {
    ushort_t* Hp = HY_base + (size_t)ez * hy_es;
#pragma unroll
    for (int qm = 0; qm < 2; ++qm)
#pragma unroll
      for (int qn = 0; qn < 2; ++qn)
#pragma unroll
        for (int np = 0; np < 2; ++np) {
          int colx = col0 + qn * 128 + wn * 32 + np * 16 + lr;
          float bv = bias[colx];
#pragma unroll
          for (int mp = 0; mp < 4; ++mp)
#pragma unroll
            for (int j = 0; j < 4; ++j) {
              int rowx = row0 + qm * 128 + wm * 64 + mp * 16 + lq + j;
              float v = acc[qm][qn][mp][np][j] + bv;
              Hp[(size_t)rowx * HDIM + colx] = f2h_bits(fmaxf(v, 0.f));
            }
        }
  } else {
    ushort_t* Yp = HY_base + (size_t)e * hy_es;
#pragma unroll
    for (int qm = 0; qm < 2; ++qm)
#pragma unroll
      for (int qn = 0; qn < 2; ++qn)
#pragma unroll
        for (int np = 0; np < 2; ++np) {
          int colx = col0 + qn * 128 + wn * 32 + np * 16 + lr;
          float bv = bias[colx];
#pragma unroll
          for (int mp = 0; mp < 4; ++mp)
#pragma unroll
            for (int j = 0; j < 4; ++j) {
              int rowx = row0 + qm * 128 + wm * 64 + mp * 16 + lq + j;
              if (rowx < ne)
                Yp[(size_t)rowx * DMODEL + colx] = f2h_bits(acc[qm][qn][mp][np][j] + bv);
            }
        }
  }
}

// ------------- old 128x128 GEMM (fallback path only) -------------
template <int EPI>
__global__ __launch_bounds__(256) void moe_gemm(
    const ushort_t* __restrict__ A_base, size_t a_es,
    const ushort_t* __restrict__ B_base, size_t b_es, int Kdim,
    int nez, int ny, int nxg,
    const int* __restrict__ counts, int e0,
    const float* __restrict__ bias_base, int bias_stride,
    ushort_t* __restrict__ H_base, size_t h_es,
    ushort_t* __restrict__ Yh,
    const int* __restrict__ tokL, const float* __restrict__ gateL,
    float* __restrict__ out) {
  int flat = blockIdx.x;
  int ez = flat % nez;
  int local = flat / nez;
  int gsz = ny * nxg;
  int g = local / gsz, rem = local % gsz;
  int row = rem / nxg, xi = rem % nxg;
  int col = g * nxg + xi;
  int e = e0 + ez;
  int ne = counts[e];
  int row0 = blockIdx.y * 0 + row * 128;
  if (row0 >= ne) return;
  int col0 = col * 128;
  const ushort_t* A = A_base + (size_t)ez * a_es;
  const ushort_t* Bt = B_base + (size_t)ez * b_es;
  const float* bias = bias_base + (size_t)e * bias_stride;
  __shared__ __align__(16) ushort_t lds_a[128 * 32];
  __shared__ __align__(16) ushort_t lds_b[128 * 32];
  int tid = threadIdx.x, wave = tid >> 6, lane = tid & 63;
  int wr = wave >> 1, wc = wave & 1;
  f32x4 acc[4][4];
#pragma unroll
  for (int m = 0; m < 4; ++m)
#pragma unroll
    for (int n = 0; n < 4; ++n) acc[m][n] = f32x4{0.f, 0.f, 0.f, 0.f};
  int srow = lane >> 2;
  int soff = (lane & 3) * 16;
  const char* Ab = (const char*)A;
  const char* Bb = (const char*)Bt;
  size_t stride = (size_t)Kdim * 2;
  int lr = lane & 15, lk = (lane >> 4) * 8;
  for (int kt = 0; kt < Kdim; kt += 32) {
#pragma unroll
    for (int i = 0; i < 2; ++i) {
      int c = wave + i * 4;
      gll16((char*)lds_a + c * 1024,
            Ab + (size_t)(row0 + c * 16 + srow) * stride + (size_t)kt * 2 + soff);
      gll16((char*)lds_b + c * 1024,
            Bb + (size_t)(col0 + c * 16 + srow) * stride + (size_t)kt * 2 + soff);
    }
    __syncthreads();
    half8 af[4], bfr[4];
#pragma unroll
    for (int m = 0; m < 4; ++m)
      af[m] = *(const half8*)&lds_a[(wr * 64 + m * 16 + lr) * 32 + lk];
#pragma unroll
    for (int n = 0; n < 4; ++n)
      bfr[n] = *(const half8*)&lds_b[(wc * 64 + n * 16 + lr) * 32 + lk];
#pragma unroll
    for (int m = 0; m < 4; ++m)
#pragma unroll
      for (int n = 0; n < 4; ++n)
        acc[m][n] = __builtin_amdgcn_mfma_f32_16x16x32_f16(af[m], bfr[n], acc[m][n], 0, 0, 0);
    __syncthreads();
  }
  int lq = (lane >> 4) * 4;
  if (EPI == 0) {
    ushort_t* H = H_base + (size_t)ez * h_es;
#pragma unroll
    for (int n = 0; n < 4; ++n) {
      int col_ = col0 + wc * 64 + n * 16 + lr;
      float bv = bias[col_];
#pragma unroll
      for (int m = 0; m < 4; ++m) {
#pragma unroll
        for (int j = 0; j < 4; ++j) {
          int r = row0 + wr * 64 + m * 16 + lq + j;
          float v = acc[m][n][j] + bv;
          H[(size_t)r * HDIM + col_] = f2h_bits(fmaxf(v, 0.f));
        }
      }
    }
  } else {
    const int* etok = tokL + e * CAP;
    const float* egate = gateL + e * CAP;
    float bv[4];
#pragma unroll
    for (int n = 0; n < 4; ++n) bv[n] = bias[col0 + wc * 64 + n * 16 + lr];
#pragma unroll
    for (int m = 0; m < 4; ++m) {
#pragma unroll
      for (int j = 0; j < 4; ++j) {
        int r = row0 + wr * 64 + m * 16 + lq + j;
        if (r < ne) {
          int tok = etok[r];
          float gt = egate[r];
#pragma unroll
          for (int n = 0; n < 4; ++n) {
            int col_ = col0 + wc * 64 + n * 16 + lr;
            atomicAdd(out + (size_t)tok * DMODEL + col_, (acc[m][n][j] + bv[n]) * gt);
          }
        }
      }
    }
  }
}

// ------------- combine: out[n] = sum_k gate_k * Yh[slot_k] -------------
__global__ __launch_bounds__(256) void combine_kernel(
    const ushort_t* __restrict__ Yh, const int* __restrict__ slotOf,
    const float* __restrict__ tgate, float* __restrict__ out) {
  int n = blockIdx.x * 2 + (threadIdx.x >> 7);
  int d = (threadIdx.x & 127) * 8;
  int s0 = slotOf[n * 2], s1 = slotOf[n * 2 + 1];
  float g0 = tgate[n * 2], g1 = tgate[n * 2 + 1];
  float acc[8];
#pragma unroll
  for (int j = 0; j < 8; ++j) acc[j] = 0.f;
  if (s0 >= 0) {
    ushort8 v = *(const ushort8*)(Yh + (size_t)s0 * DMODEL + d);
#pragma unroll
    for (int j = 0; j < 8; ++j) acc[j] = fmaf(g0, h2f(v[j]), acc[j]);
  }
  if (s1 >= 0) {
    ushort8 v = *(const ushort8*)(Yh + (size_t)s1 * DMODEL + d);
#pragma unroll
    for (int j = 0; j < 8; ++j) acc[j] = fmaf(g1, h2f(v[j]), acc[j]);
  }
  float4* o = (float4*)(out + (size_t)n * DMODEL + d);
  o[0] = float4{acc[0], acc[1], acc[2], acc[3]};
  o[1] = float4{acc[4], acc[5], acc[6], acc[7]};
}

extern "C" void kernel_launch(void* const* d_in, const int* in_sizes, int n_in,
                              void* d_out, int out_size, void* d_ws, size_t ws_size,
                              hipStream_t stream) {
  const float* x = (const float*)d_in[0];
  const float* noise = (const float*)d_in[1];
  const float* Wr = (const float*)d_in[2];
  const float* br = (const float*)d_in[3];
  const float* Wn = (const float*)d_in[4];
  const float* bn = (const float*)d_in[5];
  const float* W1 = (const float*)d_in[6];
  const float* b1 = (const float*)d_in[7];
  const float* W2 = (const float*)d_in[8];
  const float* b2 = (const float*)d_in[9];
  float* out = (float*)d_out;

  char* ws = (char*)d_ws;
  int* topi = (int*)ws;              ws += (size_t)N_TOK * 2 * 4;
  float* tgate = (float*)ws;         ws += (size_t)N_TOK * 2 * 4;
  int* tokL = (int*)ws;              ws += (size_t)NEXP * CAP * 4;
  float* gateL = (float*)ws;         ws += (size_t)NEXP * CAP * 4;
  int* slotOf = (int*)ws;            ws += (size_t)N_TOK * 2 * 4;
  int* counts = (int*)ws;            ws += 256;
  float* wrT_g = (float*)ws;         ws += (size_t)NEXP * DMODEL * 4;
  float* wnT_g = (float*)ws;         ws += (size_t)NEXP * DMODEL * 4;

  const size_t XG_E = (size_t)CAP * DMODEL;
  const size_t W1_E = (size_t)HDIM * DMODEL;
  const size_t W2_E = (size_t)DMODEL * HDIM;
  const size_t H_E  = (size_t)CAP * HDIM;
  const size_t Y_E  = (size_t)CAP * DMODEL;

  routerW_prep<<<32, 256, 0, stream>>>(Wr, Wn, wrT_g, wnT_g);
  router_kernel<<<1024, 256, 0, stream>>>(x, noise, wrT_g, wnT_g, br, bn, topi, tgate);
  scan_kernel<<<1, 1024, 0, stream>>>(topi, tgate, tokL, gateL, counts, slotOf);

  size_t used = (size_t)(ws - (char*)d_ws);
  size_t need_fast = 2ull * NEXP * (XG_E + W1_E + W2_E + Y_E) + 2ull * 4 * H_E + 1024;
  bool fast = (ws_size - used) >= need_fast;

  if (fast) {
    ushort_t* Xg_all = (ushort_t*)ws;   ws += 2ull * NEXP * XG_E;
    ushort_t* W1t_all = (ushort_t*)ws;  ws += 2ull * NEXP * W1_E;
    ushort_t* W2t_all = (ushort_t*)ws;  ws += 2ull * NEXP * W2_E;
    ushort_t* H4 = (ushort_t*)ws;       ws += 2ull * 4 * H_E;
    ushort_t* Yh = (ushort_t*)ws;       ws += 2ull * NEXP * Y_E;

    hipFuncSetAttribute(reinterpret_cast<const void*>(moe_gemm256<0>),
                        hipFuncAttributeMaxDynamicSharedMemorySize, 131072);
    hipFuncSetAttribute(reinterpret_cast<const void*>(moe_gemm256<1>),
                        hipFuncAttributeMaxDynamicSharedMemorySize, 131072);

    gather_kernel<<<dim3(CAP / 2, 1, NEXP), 256, 0, stream>>>(
        x, tokL, counts, 0, Xg_all, XG_E);
    transpose_cvt_kernel<<<dim3(HDIM / 64, DMODEL / 64, NEXP), 256, 0, stream>>>(
        W1, W1t_all, DMODEL, HDIM);
    transpose_cvt_kernel<<<dim3(DMODEL / 64, HDIM / 64, NEXP), 256, 0, stream>>>(
        W2, W2t_all, HDIM, DMODEL);
    for (int g = 0; g < 2; ++g) {
      int e0 = g * 4;
      // GEMM1: 4 experts x (16 rows x 16 cols) of 256^2
      moe_gemm256<0><<<dim3(4 * 16 * 16), 512, 131072, stream>>>(
          Xg_all + (size_t)e0 * XG_E, XG_E, W1t_all + (size_t)e0 * W1_E, W1_E,
          DMODEL, counts, e0, b1, HDIM, H4, H_E);
      // GEMM2: 4 experts x (16 rows x 4 cols) of 256^2
      moe_gemm256<1><<<dim3(4 * 16 * 4), 512, 131072, stream>>>(
          H4, H_E, W2t_all + (size_t)e0 * W2_E, W2_E,
          HDIM, counts, e0, b2, DMODEL, Yh, Y_E);
    }
    combine_kernel<<<dim3(N_TOK / 2), 256, 0, stream>>>(Yh, slotOf, tgate, out);
  } else {
    hipMemsetAsync(d_out, 0, (size_t)out_size * sizeof(float), stream);
    ushort_t* Xg = (ushort_t*)ws;   ws += 2ull * XG_E;
    ushort_t* W1t = (ushort_t*)ws;  ws += 2ull * W1_E;
    ushort_t* W2t = (ushort_t*)ws;  ws += 2ull * W2_E;
    ushort_t* H = (ushort_t*)ws;    ws += 2ull * H_E;
    for (int e = 0; e < NEXP; ++e) {
      gather_kernel<<<dim3(CAP / 2, 1, 1), 256, 0, stream>>>(
          x, tokL, counts, e, Xg, 0);
      transpose_cvt_kernel<<<dim3(HDIM / 64, DMODEL / 64, 1), 256, 0, stream>>>(
          W1 + (size_t)e * W1_E, W1t, DMODEL, HDIM);
      transpose_cvt_kernel<<<dim3(DMODEL / 64, HDIM / 64, 1), 256, 0, stream>>>(
          W2 + (size_t)e * W2_E, W2t, HDIM, DMODEL);
      moe_gemm<0><<<dim3(32 * 32), 256, 0, stream>>>(
          Xg, 0, W1t, 0, DMODEL, 1, 32, 1, counts, e, b1, HDIM,
          H, 0, nullptr, nullptr, nullptr, nullptr);
      moe_gemm<1><<<dim3(32 * 8), 256, 0, stream>>>(
          H, 0, W2t, 0, HDIM, 1, 32, 4, counts, e, b2, DMODEL,
          nullptr, 0, nullptr, tokL, gateL, out);
    }
  }
}

// Round 6
// 837.331 us; speedup vs baseline: 1.9835x; 1.0210x over previous
//
#include <hip/hip_runtime.h>

#define N_TOK 16384
#define DMODEL 1024
#define NEXP 8
#define CAP 4096
#define HDIM 4096

typedef unsigned short ushort_t;
typedef unsigned int u32;
typedef __attribute__((ext_vector_type(8))) _Float16 half8;
typedef __attribute__((ext_vector_type(8))) ushort_t ushort8;
typedef __attribute__((ext_vector_type(4))) float f32x4;

__device__ inline ushort_t f2h_bits(float f) {
  _Float16 h = (_Float16)f;
  union { _Float16 h; ushort_t u; } cv;
  cv.h = h;
  return cv.u;
}
__device__ inline float h2f(ushort_t u) {
  union { ushort_t u; _Float16 h; } cv;
  cv.u = u;
  return (float)cv.h;
}

__device__ inline void gll16(void* lds, const void* g) {
  __builtin_amdgcn_global_load_lds((const __attribute__((address_space(1))) u32*)g,
                                   (__attribute__((address_space(3))) u32*)lds,
                                   16, 0, 0);
}

// ---------------- prep: Wr/Wn [D][E] -> [E][D] f32 ----------------
__global__ __launch_bounds__(256) void routerW_prep(
    const float* __restrict__ Wr, const float* __restrict__ Wn,
    float* __restrict__ wrT, float* __restrict__ wnT) {
  int i = blockIdx.x * 256 + threadIdx.x;
  int d = i >> 3, e = i & 7;
  wrT[e * DMODEL + d] = Wr[i];
  wnT[e * DMODEL + d] = Wn[i];
}

// ---------------- router: weights from L2, 4 tokens/wave ----------------
__global__ __launch_bounds__(256, 4) void router_kernel(
    const float* __restrict__ x, const float* __restrict__ noise,
    const float* __restrict__ wrT, const float* __restrict__ wnT,
    const float* __restrict__ br, const float* __restrict__ bn,
    int* __restrict__ topi, float* __restrict__ tgate) {
  int tid = threadIdx.x;
  int wave = tid >> 6, lane = tid & 63;
  int grp0 = blockIdx.x * 4 + wave;
  for (int grp = grp0; grp < N_TOK / 4; grp += gridDim.x * 4) {
    int t0 = grp * 4;
    float aR[4][NEXP], aN[4][NEXP];
#pragma unroll
    for (int tt = 0; tt < 4; ++tt)
#pragma unroll
      for (int e = 0; e < NEXP; ++e) { aR[tt][e] = 0.f; aN[tt][e] = 0.f; }
#pragma unroll 2
    for (int it = 0; it < 16; ++it) {
      int d = it * 64 + lane;
      float xv0 = x[(size_t)t0 * DMODEL + d];
      float xv1 = x[(size_t)(t0 + 1) * DMODEL + d];
      float xv2 = x[(size_t)(t0 + 2) * DMODEL + d];
      float xv3 = x[(size_t)(t0 + 3) * DMODEL + d];
#pragma unroll
      for (int e = 0; e < NEXP; ++e) {
        float wr = wrT[e * DMODEL + d];
        float wn = wnT[e * DMODEL + d];
        aR[0][e] = fmaf(xv0, wr, aR[0][e]);
        aR[1][e] = fmaf(xv1, wr, aR[1][e]);
        aR[2][e] = fmaf(xv2, wr, aR[2][e]);
        aR[3][e] = fmaf(xv3, wr, aR[3][e]);
        aN[0][e] = fmaf(xv0, wn, aN[0][e]);
        aN[1][e] = fmaf(xv1, wn, aN[1][e]);
        aN[2][e] = fmaf(xv2, wn, aN[2][e]);
        aN[3][e] = fmaf(xv3, wn, aN[3][e]);
      }
    }
#pragma unroll
    for (int tt = 0; tt < 4; ++tt)
#pragma unroll
      for (int e = 0; e < NEXP; ++e)
#pragma unroll
        for (int off = 32; off > 0; off >>= 1) {
          aR[tt][e] += __shfl_xor(aR[tt][e], off);
          aN[tt][e] += __shfl_xor(aN[tt][e], off);
        }
#pragma unroll
    for (int tt = 0; tt < 4; ++tt) {
      if (lane == tt) {
        int t = t0 + tt;
        float v0 = -1e30f, v1 = -1e30f;
        int i0 = 0, i1 = 0;
#pragma unroll
        for (int e = 0; e < NEXP; ++e) {
          float lg = aR[tt][e] + br[e];
          float nl = aN[tt][e] + bn[e];
          float sp = fmaxf(nl, 0.f) + log1pf(expf(-fabsf(nl)));
          float nz = fmaf(noise[(size_t)t * NEXP + e], sp, lg);
          if (nz > v0) { v1 = v0; i1 = i0; v0 = nz; i0 = e; }
          else if (nz > v1) { v1 = nz; i1 = e; }
        }
        float e1 = expf(v1 - v0);
        float s = 1.f + e1;
        topi[t * 2] = i0;
        topi[t * 2 + 1] = i1;
        tgate[t * 2] = 1.f / s;
        tgate[t * 2 + 1] = e1 / s;
      }
    }
  }
}

// ------------- scan: arrival-order slots, capacity clamp, inverse map -------------
__global__ __launch_bounds__(1024) void scan_kernel(
    const int* __restrict__ topi, const float* __restrict__ tgate,
    int* __restrict__ tokL, float* __restrict__ gateL, int* __restrict__ counts,
    int* __restrict__ slotOf) {
  __shared__ int s[NEXP][1024];
  __shared__ int run[NEXP][1024];
  int t = threadIdx.x;
#pragma unroll
  for (int e = 0; e < NEXP; ++e) s[e][t] = 0;
#pragma unroll
  for (int i = 0; i < 16; ++i) {
    int n = t * 16 + i;
    s[topi[n * 2]][t]++;
    s[topi[n * 2 + 1]][t]++;
  }
  int myc[NEXP];
#pragma unroll
  for (int e = 0; e < NEXP; ++e) myc[e] = s[e][t];
  __syncthreads();
  for (int off = 1; off < 1024; off <<= 1) {
    int v[NEXP];
#pragma unroll
    for (int e = 0; e < NEXP; ++e) v[e] = (t >= off) ? s[e][t - off] : 0;
    __syncthreads();
#pragma unroll
    for (int e = 0; e < NEXP; ++e) s[e][t] += v[e];
    __syncthreads();
  }
#pragma unroll
  for (int e = 0; e < NEXP; ++e) run[e][t] = s[e][t] - myc[e];
  if (t == 1023) {
#pragma unroll
    for (int e = 0; e < NEXP; ++e) counts[e] = (s[e][1023] < CAP) ? s[e][1023] : CAP;
  }
#pragma unroll
  for (int i = 0; i < 16; ++i) {
    int n = t * 16 + i;
#pragma unroll
    for (int k = 0; k < 2; ++k) {
      int e = topi[n * 2 + k];
      int slot = run[e][t]++;
      if (slot < CAP) {
        tokL[e * CAP + slot] = n;
        gateL[e * CAP + slot] = tgate[n * 2 + k];
        slotOf[n * 2 + k] = e * CAP + slot;
      } else {
        slotOf[n * 2 + k] = -1;
      }
    }
  }
}

// ------------- gather (z = expert) -------------
__global__ __launch_bounds__(256) void gather_kernel(
    const float* __restrict__ x, const int* __restrict__ tokL,
    const int* __restrict__ counts, int e0, ushort_t* __restrict__ Xg_base,
    size_t xg_es) {
  int e = e0 + blockIdx.z;
  const int* etok = tokL + e * CAP;
  ushort_t* Xg = Xg_base + (size_t)blockIdx.z * xg_es;
  int ne = counts[e];
  int slot = blockIdx.x * 2 + (threadIdx.x >> 7);
  if (slot >= ne) return;
  int tok = etok[slot];
  int c = (threadIdx.x & 127) * 8;
  const float4* src = (const float4*)(x + (size_t)tok * DMODEL + c);
  float4 v0 = src[0], v1 = src[1];
  ushort8 o;
  o[0] = f2h_bits(v0.x); o[1] = f2h_bits(v0.y); o[2] = f2h_bits(v0.z); o[3] = f2h_bits(v0.w);
  o[4] = f2h_bits(v1.x); o[5] = f2h_bits(v1.y); o[6] = f2h_bits(v1.z); o[7] = f2h_bits(v1.w);
  *(ushort8*)(Xg + (size_t)slot * DMODEL + c) = o;
}

// ------------- transpose fp32 [R][C] -> f16 [C][R], 64x64 tiles, z = expert -------------
__global__ __launch_bounds__(256) void transpose_cvt_kernel(
    const float* __restrict__ in_base, ushort_t* __restrict__ out_base,
    int R, int C) {
  __shared__ ushort_t ldsT[64 * 66];
  const float* in = in_base + (size_t)blockIdx.z * R * C;
  ushort_t* out = out_base + (size_t)blockIdx.z * R * C;
  int t = threadIdx.x;
  int c0 = blockIdx.x * 64, r0 = blockIdx.y * 64;
  int rr = t >> 4, cc = (t & 15) * 4;
#pragma unroll
  for (int p = 0; p < 4; ++p) {
    int row = r0 + p * 16 + rr;
    float4 v = *(const float4*)&in[(size_t)row * C + c0 + cc];
    ldsT[(cc + 0) * 66 + p * 16 + rr] = f2h_bits(v.x);
    ldsT[(cc + 1) * 66 + p * 16 + rr] = f2h_bits(v.y);
    ldsT[(cc + 2) * 66 + p * 16 + rr] = f2h_bits(v.z);
    ldsT[(cc + 3) * 66 + p * 16 + rr] = f2h_bits(v.w);
  }
  __syncthreads();
  int c_o = t >> 2, r_ch = (t & 3) * 16;
  ushort8 o0, o1;
#pragma unroll
  for (int m = 0; m < 8; ++m) {
    o0[m] = ldsT[c_o * 66 + r_ch + m];
    o1[m] = ldsT[c_o * 66 + r_ch + 8 + m];
  }
  ushort_t* dst = out + (size_t)(c0 + c_o) * R + r0 + r_ch;
  *(ushort8*)dst = o0;
  *(ushort8*)(dst + 8) = o1;
}

// ===================== 256x256 x BK=64, 8-wave, double-buffered, swizzled =====================
// 2 phases / 2 barriers per K-tile; balanced 12/12 ds_reads; 16/48 MFMA clusters;
// vmcnt(4) ledger: steady-state 4 loads in flight, never drains (except final tile).
#define MFMA_Q(QM, QN, FA, FB)                                                      \
  _Pragma("unroll") for (int mp = 0; mp < 4; ++mp)                                  \
  _Pragma("unroll") for (int np = 0; np < 2; ++np)                                  \
  _Pragma("unroll") for (int ks = 0; ks < 2; ++ks)                                  \
    acc[QM][QN][mp][np] = __builtin_amdgcn_mfma_f32_16x16x32_f16(                   \
        FA[mp][ks], FB[np][ks], acc[QM][QN][mp][np], 0, 0, 0);

template <int EPI>
__global__ __launch_bounds__(512, 2) void moe_gemm256(
    const ushort_t* __restrict__ A_all, size_t a_es,
    const ushort_t* __restrict__ B_all, size_t b_es, int Kdim,
    const int* __restrict__ counts, int e0,
    const float* __restrict__ bias_base, int bias_stride,
    ushort_t* __restrict__ HY_base, size_t hy_es) {
  extern __shared__ char ldsc[];
  int flat = blockIdx.x;
  int ez = flat & 3;
  int local = flat >> 2;
  int row, col;
  if (EPI == 0) { col = local >> 4; row = local & 15; }   // 16x16, col-major walk
  else          { row = local >> 2; col = local & 3; }    // 16x4, row-major walk
  int e = e0 + ez;
  int ne = counts[e];
  int row0 = row * 256;
  if (row0 >= ne) return;
  int col0 = col * 256;

  const char* Ab = (const char*)(A_all + (size_t)ez * a_es) + (size_t)row0 * Kdim * 2;
  const char* Bb = (const char*)(B_all + (size_t)ez * b_es) + (size_t)col0 * Kdim * 2;
  const size_t gstrA = (size_t)Kdim * 2;

  int tid = threadIdx.x;
  int wave = tid >> 6, lane = tid & 63;
  int wm = wave >> 2, wn = wave & 3;       // 2 x 4 waves over each 128x128 quadrant
  int lr = lane & 15, lg = lane >> 4;

  f32x4 acc[2][2][4][2];
#pragma unroll
  for (int qm = 0; qm < 2; ++qm)
#pragma unroll
    for (int qn = 0; qn < 2; ++qn)
#pragma unroll
      for (int mp = 0; mp < 4; ++mp)
#pragma unroll
        for (int np = 0; np < 2; ++np) acc[qm][qn][mp][np] = f32x4{0.f, 0.f, 0.f, 0.f};

  // stage one 16KB half-tile: half 0/1 = A rows 0-127/128-255; 2/3 = B rows.
  auto STAGE = [&](char* obuf, int half, int tt) {
    const char* gb = (half < 2) ? (Ab + (size_t)(half * 128) * gstrA)
                                : (Bb + (size_t)((half - 2) * 128) * gstrA);
    gb += (size_t)tt * 128;                 // K offset in bytes (64 elems)
    char* lb = obuf + half * 16384 + wave * 1024;
#pragma unroll
    for (int i = 0; i < 2; ++i) {
      int o = (i * 512 + tid) * 16;
      int r = o >> 7;
      int lc = ((o >> 4) & 7) ^ (r & 7);    // inverse swizzle on global source
      gll16(lb + i * 8192, gb + (size_t)r * gstrA + lc * 16);
    }
  };
  auto LDA = [&](const char* buf, int qm, int mp, int ks) -> half8 {
    int r = qm * 128 + wm * 64 + mp * 16 + lr;
    int c = ((ks * 4 + lg) ^ (r & 7)) * 16;
    return *(const half8*)(buf + r * 128 + c);
  };
  auto LDB = [&](const char* buf, int qn, int np, int ks) -> half8 {
    int r = qn * 128 + wn * 32 + np * 16 + lr;
    int c = ((ks * 4 + lg) ^ (r & 7)) * 16;
    return *(const half8*)(buf + 32768 + r * 128 + c);
  };

  int NT = Kdim >> 6;
  // prologue: stage tile 0 in order h0,h2,h1,h3 so vmcnt(4) covers exactly {A0,B0}
  STAGE(ldsc, 0, 0); STAGE(ldsc, 2, 0); STAGE(ldsc, 1, 0); STAGE(ldsc, 3, 0);
  asm volatile("s_waitcnt vmcnt(4)" ::: "memory");
  __builtin_amdgcn_s_barrier();

  half8 fA0[4][2], fA1[4][2], fB0[2][2], fB1[2][2];
  for (int t = 0; t < NT; ++t) {
    char* bufc = ldsc + (t & 1) * 65536;
    char* obufc = ldsc + ((t & 1) ^ 1) * 65536;
    bool pf = (t + 1 < NT);
    // ---- Phase 1: Q00 (A0,B0 globally landed at entry) ----
#pragma unroll
    for (int mp = 0; mp < 4; ++mp)
#pragma unroll
      for (int ks = 0; ks < 2; ++ks) fA0[mp][ks] = LDA(bufc, 0, mp, ks);
#pragma unroll
    for (int np = 0; np < 2; ++np)
#pragma unroll
      for (int ks = 0; ks < 2; ++ks) fB0[np][ks] = LDB(bufc, 0, np, ks);
    if (pf) { STAGE(obufc, 0, t + 1); STAGE(obufc, 2, t + 1); }   // A0', B0'
    __builtin_amdgcn_s_setprio(1);
    MFMA_Q(0, 0, fA0, fB0);
    __builtin_amdgcn_s_setprio(0);
    if (pf) { asm volatile("s_waitcnt vmcnt(4)" ::: "memory"); }  // my A1,B1 landed
    else    { asm volatile("s_waitcnt vmcnt(0)" ::: "memory"); }
    __builtin_amdgcn_s_barrier();                                  // A1,B1 global
    // ---- Phase 2: Q01, Q10, Q11 ----
#pragma unroll
    for (int np = 0; np < 2; ++np)
#pragma unroll
      for (int ks = 0; ks < 2; ++ks) fB1[np][ks] = LDB(bufc, 1, np, ks);
#pragma unroll
    for (int mp = 0; mp < 4; ++mp)
#pragma unroll
      for (int ks = 0; ks < 2; ++ks) fA1[mp][ks] = LDA(bufc, 1, mp, ks);
    if (pf) { STAGE(obufc, 1, t + 1); STAGE(obufc, 3, t + 1); }   // A1', B1'
    __builtin_amdgcn_s_setprio(1);
    MFMA_Q(0, 1, fA0, fB1);
    MFMA_Q(1, 0, fA1, fB0);
    MFMA_Q(1, 1, fA1, fB1);
    __builtin_amdgcn_s_setprio(0);
    if (pf) {
      asm volatile("s_waitcnt vmcnt(4)" ::: "memory");             // A0',B0' landed
      __builtin_amdgcn_s_barrier();                                // A0',B0' global
    }
  }

  const float* bias = bias_base + (size_t)e * bias_stride;
  int lq = lg * 4;
  if (EPI == 0) {
    ushort_t* Hp = HY_base + (size_t)ez * hy_es;
#pragma unroll
    for (int qm = 0; qm < 2; ++qm)
#pragma unroll
      for (int qn = 0; qn < 2; ++qn)
#pragma unroll
        for (int np = 0; np < 2; ++np) {
          int colx = col0 + qn * 128 + wn * 32 + np * 16 + lr;
          float bv = bias[colx];
#pragma unroll
          for (int mp = 0; mp < 4; ++mp)
#pragma unroll
            for (int j = 0; j < 4; ++j) {
              int rowx = row0 + qm * 128 + wm * 64 + mp * 16 + lq + j;
              float v = acc[qm][qn][mp][np][j] + bv;
              Hp[(size_t)rowx * HDIM + colx] = f2h_bits(fmaxf(v, 0.f));
            }
        }
  } else {
    ushort_t* Yp = HY_base + (size_t)e * hy_es;
#pragma unroll
    for (int qm = 0; qm < 2; ++qm)
#pragma unroll
      for (int qn = 0; qn < 2; ++qn)
#pragma unroll
        for (int np = 0; np < 2; ++np) {
          int colx = col0 + qn * 128 + wn * 32 + np * 16 + lr;
          float bv = bias[colx];
#pragma unroll
          for (int mp = 0; mp < 4; ++mp)
#pragma unroll
            for (int j = 0; j < 4; ++j) {
              int rowx = row0 + qm * 128 + wm * 64 + mp * 16 + lq + j;
              if (rowx < ne)
                Yp[(size_t)rowx * DMODEL + colx] = f2h_bits(acc[qm][qn][mp][np][j] + bv);
            }
        }
  }
}

// ------------- old 128x128 GEMM (fallback path only) -------------
template <int EPI>
__global__ __launch_bounds__(256) void moe_gemm(
    const ushort_t* __restrict__ A_base, size_t a_es,
    const ushort_t* __restrict__ B_base, size_t b_es, int Kdim,
    int nez, int ny, int nxg,
    const int* __restrict__ counts, int e0,
    const float* __restrict__ bias_base, int bias_stride,
    ushort_t* __restrict__ H_base, size_t h_es,
    ushort_t* __restrict__ Yh,
    const int* __restrict__ tokL, const float* __restrict__ gateL,
    float* __restrict__ out) {
  int flat = blockIdx.x;
  int ez = flat % nez;
  int local = flat / nez;
  int gsz = ny * nxg;
  int g = local / gsz, rem = local % gsz;
  int row = rem / nxg, xi = rem % nxg;
  int col = g * nxg + xi;
  int e = e0 + ez;
  int ne = counts[e];
  int row0 = row * 128;
  if (row0 >= ne) return;
  int col0 = col * 128;
  const ushort_t* A = A_base + (size_t)ez * a_es;
  const ushort_t* Bt = B_base + (size_t)ez * b_es;
  const float* bias = bias_base + (size_t)e * bias_stride;
  __shared__ __align__(16) ushort_t lds_a[128 * 32];
  __shared__ __align__(16) ushort_t lds_b[128 * 32];
  int tid = threadIdx.x, wave = tid >> 6, lane = tid & 63;
  int wr = wave >> 1, wc = wave & 1;
  f32x4 acc[4][4];
#pragma unroll
  for (int m = 0; m < 4; ++m)
#pragma unroll
    for (int n = 0; n < 4; ++n) acc[m][n] = f32x4{0.f, 0.f, 0.f, 0.f};
  int srow = lane >> 2;
  int soff = (lane & 3) * 16;
  const char* Ab = (const char*)A;
  const char* Bb = (const char*)Bt;
  size_t stride = (size_t)Kdim * 2;
  int lr = lane & 15, lk = (lane >> 4) * 8;
  for (int kt = 0; kt < Kdim; kt += 32) {
#pragma unroll
    for (int i = 0; i < 2; ++i) {
      int c = wave + i * 4;
      gll16((char*)lds_a + c * 1024,
            Ab + (size_t)(row0 + c * 16 + srow) * stride + (size_t)kt * 2 + soff);
      gll16((char*)lds_b + c * 1024,
            Bb + (size_t)(col0 + c * 16 + srow) * stride + (size_t)kt * 2 + soff);
    }
    __syncthreads();
    half8 af[4], bfr[4];
#pragma unroll
    for (int m = 0; m < 4; ++m)
      af[m] = *(const half8*)&lds_a[(wr * 64 + m * 16 + lr) * 32 + lk];
#pragma unroll
    for (int n = 0; n < 4; ++n)
      bfr[n] = *(const half8*)&lds_b[(wc * 64 + n * 16 + lr) * 32 + lk];
#pragma unroll
    for (int m = 0; m < 4; ++m)
#pragma unroll
      for (int n = 0; n < 4; ++n)
        acc[m][n] = __builtin_amdgcn_mfma_f32_16x16x32_f16(af[m], bfr[n], acc[m][n], 0, 0, 0);
    __syncthreads();
  }
  int lq = (lane >> 4) * 4;
  if (EPI == 0) {
    ushort_t* H = H_base + (size_t)ez * h_es;
#pragma unroll
    for (int n = 0; n < 4; ++n) {
      int col_ = col0 + wc * 64 + n * 16 + lr;
      float bv = bias[col_];
#pragma unroll
      for (int m = 0; m < 4; ++m) {
#pragma unroll
        for (int j = 0; j < 4; ++j) {
          int r = row0 + wr * 64 + m * 16 + lq + j;
          float v = acc[m][n][j] + bv;
          H[(size_t)r * HDIM + col_] = f2h_bits(fmaxf(v, 0.f));
        }
      }
    }
  } else {
    const int* etok = tokL + e * CAP;
    const float* egate = gateL + e * CAP;
    float bv[4];
#pragma unroll
    for (int n = 0; n < 4; ++n) bv[n] = bias[col0 + wc * 64 + n * 16 + lr];
#pragma unroll
    for (int m = 0; m < 4; ++m) {
#pragma unroll
      for (int j = 0; j < 4; ++j) {
        int r = row0 + wr * 64 + m * 16 + lq + j;
        if (r < ne) {
          int tok = etok[r];
          float gt = egate[r];
#pragma unroll
          for (int n = 0; n < 4; ++n) {
            int col_ = col0 + wc * 64 + n * 16 + lr;
            atomicAdd(out + (size_t)tok * DMODEL + col_, (acc[m][n][j] + bv[n]) * gt);
          }
        }
      }
    }
  }
}

// ------------- combine: out[n] = sum_k gate_k * Yh[slot_k] -------------
__global__ __launch_bounds__(256) void combine_kernel(
    const ushort_t* __restrict__ Yh, const int* __restrict__ slotOf,
    const float* __restrict__ tgate, float* __restrict__ out) {
  int n = blockIdx.x * 2 + (threadIdx.x >> 7);
  int d = (threadIdx.x & 127) * 8;
  int s0 = slotOf[n * 2], s1 = slotOf[n * 2 + 1];
  float g0 = tgate[n * 2], g1 = tgate[n * 2 + 1];
  float acc[8];
#pragma unroll
  for (int j = 0; j < 8; ++j) acc[j] = 0.f;
  if (s0 >= 0) {
    ushort8 v = *(const ushort8*)(Yh + (size_t)s0 * DMODEL + d);
#pragma unroll
    for (int j = 0; j < 8; ++j) acc[j] = fmaf(g0, h2f(v[j]), acc[j]);
  }
  if (s1 >= 0) {
    ushort8 v = *(const ushort8*)(Yh + (size_t)s1 * DMODEL + d);
#pragma unroll
    for (int j = 0; j < 8; ++j) acc[j] = fmaf(g1, h2f(v[j]), acc[j]);
  }
  float4* o = (float4*)(out + (size_t)n * DMODEL + d);
  o[0] = float4{acc[0], acc[1], acc[2], acc[3]};
  o[1] = float4{acc[4], acc[5], acc[6], acc[7]};
}

extern "C" void kernel_launch(void* const* d_in, const int* in_sizes, int n_in,
                              void* d_out, int out_size, void* d_ws, size_t ws_size,
                              hipStream_t stream) {
  const float* x = (const float*)d_in[0];
  const float* noise = (const float*)d_in[1];
  const float* Wr = (const float*)d_in[2];
  const float* br = (const float*)d_in[3];
  const float* Wn = (const float*)d_in[4];
  const float* bn = (const float*)d_in[5];
  const float* W1 = (const float*)d_in[6];
  const float* b1 = (const float*)d_in[7];
  const float* W2 = (const float*)d_in[8];
  const float* b2 = (const float*)d_in[9];
  float* out = (float*)d_out;

  char* ws = (char*)d_ws;
  int* topi = (int*)ws;              ws += (size_t)N_TOK * 2 * 4;
  float* tgate = (float*)ws;         ws += (size_t)N_TOK * 2 * 4;
  int* tokL = (int*)ws;              ws += (size_t)NEXP * CAP * 4;
  float* gateL = (float*)ws;         ws += (size_t)NEXP * CAP * 4;
  int* slotOf = (int*)ws;            ws += (size_t)N_TOK * 2 * 4;
  int* counts = (int*)ws;            ws += 256;
  float* wrT_g = (float*)ws;         ws += (size_t)NEXP * DMODEL * 4;
  float* wnT_g = (float*)ws;         ws += (size_t)NEXP * DMODEL * 4;

  const size_t XG_E = (size_t)CAP * DMODEL;
  const size_t W1_E = (size_t)HDIM * DMODEL;
  const size_t W2_E = (size_t)DMODEL * HDIM;
  const size_t H_E  = (size_t)CAP * HDIM;
  const size_t Y_E  = (size_t)CAP * DMODEL;

  routerW_prep<<<32, 256, 0, stream>>>(Wr, Wn, wrT_g, wnT_g);
  router_kernel<<<1024, 256, 0, stream>>>(x, noise, wrT_g, wnT_g, br, bn, topi, tgate);
  scan_kernel<<<1, 1024, 0, stream>>>(topi, tgate, tokL, gateL, counts, slotOf);

  size_t used = (size_t)(ws - (char*)d_ws);
  size_t need_fast = 2ull * NEXP * (XG_E + W1_E + W2_E + Y_E) + 2ull * 4 * H_E + 1024;
  bool fast = (ws_size - used) >= need_fast;

  if (fast) {
    ushort_t* Xg_all = (ushort_t*)ws;   ws += 2ull * NEXP * XG_E;
    ushort_t* W1t_all = (ushort_t*)ws;  ws += 2ull * NEXP * W1_E;
    ushort_t* W2t_all = (ushort_t*)ws;  ws += 2ull * NEXP * W2_E;
    ushort_t* H4 = (ushort_t*)ws;       ws += 2ull * 4 * H_E;
    ushort_t* Yh = (ushort_t*)ws;       ws += 2ull * NEXP * Y_E;

    hipFuncSetAttribute(reinterpret_cast<const void*>(moe_gemm256<0>),
                        hipFuncAttributeMaxDynamicSharedMemorySize, 131072);
    hipFuncSetAttribute(reinterpret_cast<const void*>(moe_gemm256<1>),
                        hipFuncAttributeMaxDynamicSharedMemorySize, 131072);

    gather_kernel<<<dim3(CAP / 2, 1, NEXP), 256, 0, stream>>>(
        x, tokL, counts, 0, Xg_all, XG_E);
    transpose_cvt_kernel<<<dim3(HDIM / 64, DMODEL / 64, NEXP), 256, 0, stream>>>(
        W1, W1t_all, DMODEL, HDIM);
    transpose_cvt_kernel<<<dim3(DMODEL / 64, HDIM / 64, NEXP), 256, 0, stream>>>(
        W2, W2t_all, HDIM, DMODEL);
    for (int g = 0; g < 2; ++g) {
      int e0 = g * 4;
      // GEMM1: 4 experts x (16 rows x 16 cols) of 256^2
      moe_gemm256<0><<<dim3(4 * 16 * 16), 512, 131072, stream>>>(
          Xg_all + (size_t)e0 * XG_E, XG_E, W1t_all + (size_t)e0 * W1_E, W1_E,
          DMODEL, counts, e0, b1, HDIM, H4, H_E);
      // GEMM2: 4 experts x (16 rows x 4 cols) of 256^2
      moe_gemm256<1><<<dim3(4 * 16 * 4), 512, 131072, stream>>>(
          H4, H_E, W2t_all + (size_t)e0 * W2_E, W2_E,
          HDIM, counts, e0, b2, DMODEL, Yh, Y_E);
    }
    combine_kernel<<<dim3(N_TOK / 2), 256, 0, stream>>>(Yh, slotOf, tgate, out);
  } else {
    hipMemsetAsync(d_out, 0, (size_t)out_size * sizeof(float), stream);
    ushort_t* Xg = (ushort_t*)ws;   ws += 2ull * XG_E;
    ushort_t* W1t = (ushort_t*)ws;  ws += 2ull * W1_E;
    ushort_t* W2t = (ushort_t*)ws;  ws += 2ull * W2_E;
    ushort_t* H = (ushort_t*)ws;    ws += 2ull * H_E;
    for (int e = 0; e < NEXP; ++e) {
      gather_kernel<<<dim3(CAP / 2, 1, 1), 256, 0, stream>>>(
          x, tokL, counts, e, Xg, 0);
      transpose_cvt_kernel<<<dim3(HDIM / 64, DMODEL / 64, 1), 256, 0, stream>>>(
          W1 + (size_t)e * W1_E, W1t, DMODEL, HDIM);
      transpose_cvt_kernel<<<dim3(DMODEL / 64, HDIM / 64, 1), 256, 0, stream>>>(
          W2 + (size_t)e * W2_E, W2t, HDIM, DMODEL);
      moe_gemm<0><<<dim3(32 * 32), 256, 0, stream>>>(
          Xg, 0, W1t, 0, DMODEL, 1, 32, 1, counts, e, b1, HDIM,
          H, 0, nullptr, nullptr, nullptr, nullptr);
      moe_gemm<1><<<dim3(32 * 8), 256, 0, stream>>>(
          H, 0, W2t, 0, HDIM, 1, 32, 4, counts, e, b2, DMODEL,
          nullptr, 0, nullptr, tokL, gateL, out);
    }
  }
}